// Round 6
// baseline (1281.177 us; speedup 1.0000x reference)
//
#include <hip/hip_runtime.h>
#include <cstdio>

// Problem constants
#define BATCH 256
#define SEQL 256
#define NPOS 259            // 3 + SEQL
#define TTOK (BATCH*NPOS)   // 66304 = 518 * 128
#define HD 128
#define NHEAD 8
#define FF 512
#define DEPTH 4
#define CVOC 50001

typedef unsigned short u16;
typedef unsigned int u32;
typedef __bf16 bf16x8 __attribute__((ext_vector_type(8)));
typedef float f32x4 __attribute__((ext_vector_type(4)));
typedef float f32x16 __attribute__((ext_vector_type(16)));

typedef const __attribute__((address_space(1))) u32 gas_u32;
typedef __attribute__((address_space(3))) u32 las_u32;
#define GLOAD16(gptr, lptr) \
  __builtin_amdgcn_global_load_lds((gas_u32*)(gptr), (las_u32*)(lptr), 16, 0, 0)

__device__ __forceinline__ u16 f2bf(float f) {
  u32 i = __float_as_uint(f);
  u32 r = (i + 0x7FFFu + ((i >> 16) & 1u)) >> 16;   // RNE
  return (u16)r;
}

// ---------------------------------------------------------------- transpose + downcast
// in (fp32): [D][K][N] -> out (bf16): [D][N][K]
__global__ void k_transpose(const float* __restrict__ in, u16* __restrict__ out,
                            int D, int K, int N) {
  int idx = blockIdx.x * 256 + threadIdx.x;
  int total = D * K * N;
  if (idx >= total) return;
  int k = idx % K; int rem = idx / K; int n = rem % N; int d = rem / N;
  out[idx] = f2bf(in[(d * K + k) * N + n]);
}

// ---------------------------------------------------------------- build x
__global__ __launch_bounds__(128)
void k_build(const int* __restrict__ item_seq, const int* __restrict__ act_seq,
             const int* __restrict__ tdiff,
             const int* __restrict__ ucv, const int* __restrict__ ucl, const float* __restrict__ unum,
             const int* __restrict__ icv, const int* __restrict__ icl, const float* __restrict__ inum,
             const float* __restrict__ item_t, const float* __restrict__ act_t,
             const float* __restrict__ time_t, const float* __restrict__ cat_t,
             const float* __restrict__ numW, const float* __restrict__ gtok,
             float* __restrict__ x) {
  int pos = blockIdx.x, b = blockIdx.y, h = threadIdx.x;
  float v;
  if (pos == 0) {
    v = gtok[h];
  } else if (pos <= 2) {
    const int* cv = (pos == 1) ? ucv : icv;
    const int* cl = (pos == 1) ? ucl : icl;
    const float* nm = (pos == 1) ? unum : inum;
    float acc = 0.f;
    for (int f = 0; f < 8; ++f) {
      float s = 0.f;
      for (int k = 0; k < 8; ++k) {
        int idx = cv[(b * 8 + f) * 8 + k];
        s += cat_t[((size_t)f * CVOC + idx) * HD + h];
      }
      acc += s / (float)cl[b * 8 + f];
    }
    for (int f = 0; f < 4; ++f)
      for (int d = 0; d < 32; ++d)
        acc += nm[(b * 4 + f) * 32 + d] * numW[(f * 32 + d) * HD + h];
    v = acc * (1.f / 12.f);
  } else {
    int l = pos - 3;
    v = item_t[(size_t)item_seq[b * SEQL + l] * HD + h]
      + act_t[(size_t)act_seq[b * SEQL + l] * HD + h]
      + time_t[(size_t)tdiff[b * SEQL + l] * HD + h];
  }
  x[((size_t)b * NPOS + pos) * HD + h] = v;
}

// ---------------------------------------------------------------- GEMM (MFMA, BK=128)
// Y[T x N] = act(op(X)[T x K] @ W + bias); WT[N][K] bf16.
// Tile 128x128, 4 waves 2x2, 64x64/wave (4x4 frags). BK=128 staged as 4
// subtiles [kt][128][32] with XOR column-segment swizzle (phys p holds logical
// p^((r>>1)&3)); one barrier pair per 128-K chunk, 64 MFMA between.
// LN: A is fp32 [T][128], layernorm(g,be) applied during staging (K must be 128).
// ACT 1 = exact gelu; QS: output cols<128 *= 0.25; RESID: += into fp32 outp.
template <int ACT, bool RESID, bool QS, bool LN>
__global__ __launch_bounds__(256)
void k_gemm2(const void* __restrict__ Xp, const u16* __restrict__ WT,
             const float* __restrict__ g, const float* __restrict__ be,
             const float* __restrict__ bias, void* __restrict__ outp,
             int K, int N) {
  __shared__ __align__(16) u16 lA[128 * 128];
  __shared__ __align__(16) u16 lB[128 * 128];
  const int tid = threadIdx.x;
  const int wave = tid >> 6, lane = tid & 63;
  const int row0 = blockIdx.x * 128;
  const int n0 = blockIdx.y * 128;
  const int wr = (wave >> 1) * 64, wc = (wave & 1) * 64;
  const int q = lane & 15, cg = lane >> 4;
  const int rdoff = ((cg ^ ((q >> 1) & 3)) << 3);
  const int swz = (((lane & 3) ^ ((lane >> 3) & 3)) << 3);   // staging col swizzle (u16)

  // LN-fused A staging (K == 128): thread t handles row t>>1, half t&1.
  if (LN) {
    const float* Xf = (const float*)Xp;
    const int r = tid >> 1, hh = tid & 1;
    const float* xr = Xf + (size_t)(row0 + r) * 128 + hh * 64;
    float v[64];
    #pragma unroll
    for (int i = 0; i < 16; ++i)
      *(float4*)&v[i * 4] = *(const float4*)&xr[i * 4];
    float s = 0.f, s2 = 0.f;
    #pragma unroll
    for (int i = 0; i < 64; ++i) { s += v[i]; s2 += v[i] * v[i]; }
    s += __shfl_xor(s, 1); s2 += __shfl_xor(s2, 1);
    float mean = s * (1.f / 128.f);
    float rstd = rsqrtf(s2 * (1.f / 128.f) - mean * mean + 1e-5f);
    const int sel = (r >> 1) & 3;
    #pragma unroll
    for (int jj = 0; jj < 8; ++jj) {
      int cbase = hh * 64 + jj * 8;
      u16 tmp[8];
      #pragma unroll
      for (int e = 0; e < 8; ++e) {
        int c = cbase + e;
        tmp[e] = f2bf((v[jj * 8 + e] - mean) * rstd * g[c] + be[c]);
      }
      int kt = cbase >> 5;
      int p = (jj & 3) ^ sel;
      *(uint4*)&lA[kt * 4096 + r * 32 + p * 8] = *(uint4*)tmp;
    }
  }

  const u16* Xb = (const u16*)Xp;
  f32x4 acc[4][4] = {};
  const int kchunks = K >> 7;
  for (int kb = 0; kb < kchunks; ++kb) {
    __syncthreads();
    if (!LN) {
      #pragma unroll
      for (int s = 0; s < 8; ++s) {
        int kt = s & 3, rg = 2 * wave + (s >> 2);
        int r = rg * 16 + (lane >> 2);
        int scol = (kb << 7) + kt * 32 + swz;
        GLOAD16(Xb + (size_t)(row0 + r) * K + scol, &lA[kt * 4096 + rg * 512]);
      }
    }
    #pragma unroll
    for (int s = 0; s < 8; ++s) {
      int kt = s & 3, rg = 2 * wave + (s >> 2);
      int r = rg * 16 + (lane >> 2);
      int scol = (kb << 7) + kt * 32 + swz;
      GLOAD16(WT + (size_t)(n0 + r) * K + scol, &lB[kt * 4096 + rg * 512]);
    }
    __syncthreads();                 // compiler drains vmcnt/lgkmcnt here
    #pragma unroll
    for (int kt = 0; kt < 4; ++kt) {
      bf16x8 af[4], bf[4];
      #pragma unroll
      for (int i = 0; i < 4; ++i)
        af[i] = *(const bf16x8*)&lA[kt * 4096 + (wr + i * 16 + q) * 32 + rdoff];
      #pragma unroll
      for (int j = 0; j < 4; ++j)
        bf[j] = *(const bf16x8*)&lB[kt * 4096 + (wc + j * 16 + q) * 32 + rdoff];
      #pragma unroll
      for (int i = 0; i < 4; ++i)
        #pragma unroll
        for (int j = 0; j < 4; ++j)
          acc[i][j] = __builtin_amdgcn_mfma_f32_16x16x32_bf16(af[i], bf[j], acc[i][j], 0, 0, 0);
    }
  }
  const int rg4 = cg * 4;
  #pragma unroll
  for (int i = 0; i < 4; ++i) {
    #pragma unroll
    for (int j = 0; j < 4; ++j) {
      int col = n0 + wc + j * 16 + q;
      float bv = bias[col];
      float scl = (QS && col < 128) ? 0.25f : 1.f;
      #pragma unroll
      for (int jj = 0; jj < 4; ++jj) {
        int row = row0 + wr + i * 16 + rg4 + jj;
        float v = acc[i][j][jj] + bv;
        if (ACT == 1) v = 0.5f * v * (1.f + erff(v * 0.70710678118654752f));
        if (QS) v *= scl;
        if (RESID) ((float*)outp)[(size_t)row * N + col] += v;
        else ((u16*)outp)[(size_t)row * N + col] = f2bf(v);
      }
    }
  }
}

// ---------------------------------------------------------------- attention (32x32 MFMA flash)
// grid (NHEAD, BATCH), 256 threads = 4 waves. qkv: [T][384] bf16 (q pre-scaled by 0.25).
#define VSTR2 296   // Vt row stride (u16)
__global__ __launch_bounds__(256)
void k_attn(const u16* __restrict__ qkv, const int* __restrict__ mask,
            u16* __restrict__ out) {
  int h = blockIdx.x, b = blockIdx.y;
  __shared__ __align__(16) u16 Klin[9 * 512];     // frag-linear K: [tile][lane][8]
  __shared__ __align__(16) u16 Vt[16 * VSTR2];    // V transposed: [d][k]
  __shared__ int part[4];
  const int tid = threadIdx.x;
  int mv = (mask[b * SEQL + tid] != 0) ? 1 : 0;
  #pragma unroll
  for (int o = 32; o; o >>= 1) mv += __shfl_xor(mv, o);
  if ((tid & 63) == 0) part[tid >> 6] = mv;
  for (int idx = tid; idx < 576; idx += 256) {
    int r = idx >> 1, h2 = idx & 1;
    uint4 val = make_uint4(0, 0, 0, 0);
    if (r < NPOS)
      val = *(const uint4*)&qkv[((size_t)(b * NPOS + r)) * 384 + h * 16 + 128 + h2 * 8];
    *(uint4*)&Klin[(r >> 5) * 512 + h2 * 256 + (r & 31) * 8] = val;
  }
  for (int r = tid; r < 288; r += 256) {
    u16 tmp[16];
    if (r < NPOS) {
      const u16* vp = &qkv[((size_t)(b * NPOS + r)) * 384 + h * 16 + 256];
      *(uint4*)&tmp[0] = *(const uint4*)&vp[0];
      *(uint4*)&tmp[8] = *(const uint4*)&vp[8];
    } else {
      #pragma unroll
      for (int d = 0; d < 16; ++d) tmp[d] = 0;
    }
    #pragma unroll
    for (int d = 0; d < 16; ++d) Vt[d * VSTR2 + r] = tmp[d];
  }
  __syncthreads();
  const int nvalid = part[0] + part[1] + part[2] + part[3] + 3;
  const int ktiles = (nvalid + 31) >> 5;
  const int wave = tid >> 6, lane = tid & 63;
  const int q5 = lane & 31, hi = lane >> 5;
  const f32x16 zf = {};
  for (int qt = wave; qt < 9; qt += 4) {
    int qrow = qt * 32 + q5;
    int qr = (qrow < NPOS) ? qrow : (NPOS - 1);
    bf16x8 qf = *(const bf16x8*)&qkv[((size_t)(b * NPOS + qr)) * 384 + h * 16 + hi * 8];
    float m = -1e30f, l = 0.f;
    f32x16 acc = {};
    for (int kt = 0; kt < ktiles; ++kt) {
      bf16x8 kf = *(const bf16x8*)&Klin[kt * 512 + lane * 8];
      f32x16 s4 = __builtin_amdgcn_mfma_f32_32x32x16_bf16(kf, qf, zf, 0, 0, 0);
      float p[16];
      float tmax = -1e30f;
      #pragma unroll
      for (int r = 0; r < 16; ++r) {
        int kr = kt * 32 + (r & 3) + 8 * (r >> 2) + 4 * hi;
        float v = (kr < nvalid) ? s4[r] : -1e30f;
        p[r] = v;
        tmax = fmaxf(tmax, v);
      }
      tmax = fmaxf(tmax, __shfl_xor(tmax, 32));
      float mnew = fmaxf(m, tmax);
      float fac = __expf(m - mnew);
      float tsum = 0.f;
      #pragma unroll
      for (int r = 0; r < 16; ++r) { p[r] = __expf(p[r] - mnew); tsum += p[r]; }
      tsum += __shfl_xor(tsum, 32);
      l = l * fac + tsum;
      m = mnew;
      #pragma unroll
      for (int r = 0; r < 8; ++r) acc[r] *= fac;   // regs 8-15 stay 0
      u32 w[8], xw[8];
      #pragma unroll
      for (int i = 0; i < 8; ++i)
        asm("v_cvt_pk_bf16_f32 %0, %1, %2" : "=v"(w[i]) : "v"(p[2 * i]), "v"(p[2 * i + 1]));
      #pragma unroll
      for (int i = 0; i < 8; ++i) xw[i] = (u32)__shfl_xor((int)w[i], 32);
      union { u32 u[4]; bf16x8 v; } f1, f2;
      if (hi) {
        f1.u[0] = xw[2]; f1.u[1] = xw[3]; f1.u[2] = w[2]; f1.u[3] = w[3];
        f2.u[0] = xw[6]; f2.u[1] = xw[7]; f2.u[2] = w[6]; f2.u[3] = w[7];
      } else {
        f1.u[0] = w[0]; f1.u[1] = w[1]; f1.u[2] = xw[0]; f1.u[3] = xw[1];
        f2.u[0] = w[4]; f2.u[1] = w[5]; f2.u[2] = xw[4]; f2.u[3] = xw[5];
      }
      bf16x8 vf0 = {}, vf1 = {};
      if (q5 < 16) {
        vf0 = *(const bf16x8*)&Vt[q5 * VSTR2 + kt * 32 + hi * 8];
        vf1 = *(const bf16x8*)&Vt[q5 * VSTR2 + kt * 32 + 16 + hi * 8];
      }
      acc = __builtin_amdgcn_mfma_f32_32x32x16_bf16(vf0, f1.v, acc, 0, 0, 0);
      acc = __builtin_amdgcn_mfma_f32_32x32x16_bf16(vf1, f2.v, acc, 0, 0, 0);
    }
    if (qrow < NPOS) {
      float linv = 1.f / l;
      u16* op = &out[((size_t)(b * NPOS + qrow)) * HD + h * 16];
      u32 w0 = (u32)f2bf(acc[0] * linv) | ((u32)f2bf(acc[1] * linv) << 16);
      u32 w1 = (u32)f2bf(acc[2] * linv) | ((u32)f2bf(acc[3] * linv) << 16);
      u32 w2 = (u32)f2bf(acc[4] * linv) | ((u32)f2bf(acc[5] * linv) << 16);
      u32 w3 = (u32)f2bf(acc[6] * linv) | ((u32)f2bf(acc[7] * linv) << 16);
      *(uint2*)&op[4 * hi] = make_uint2(w0, w1);
      *(uint2*)&op[8 + 4 * hi] = make_uint2(w2, w3);
    }
  }
}

// ---------------------------------------------------------------- head
__global__ __launch_bounds__(128)
void k_head(const float* __restrict__ x, const float* __restrict__ bw,
            const float* __restrict__ bb, const float* __restrict__ cw,
            const float* __restrict__ cb, float* __restrict__ dout) {
  int b = blockIdx.x, n = threadIdx.x;
  __shared__ float lat[HD];
  __shared__ float redp[2], redss[2];
  float lv = x[((size_t)b * NPOS) * HD + n];
  lat[n] = lv;
  __syncthreads();
  float t = 0.f;
  for (int k = 0; k < HD; ++k) t += lat[k] * bw[k * HD + n];
  t += bb[n];
  t = fmaxf(t, 0.f);
  float p = t * cw[n];
  float ss = lv * lv;
  #pragma unroll
  for (int o = 32; o; o >>= 1) { p += __shfl_xor(p, o); ss += __shfl_xor(ss, o); }
  if ((n & 63) == 0) { redp[n >> 6] = p; redss[n >> 6] = ss; }
  __syncthreads();
  float psum = redp[0] + redp[1];
  float ssum = redss[0] + redss[1];
  if (n == 0) dout[b] = psum + cb[0];
  float nrm = fmaxf(sqrtf(ssum), 1e-12f);
  dout[256 + (size_t)b * HD + n] = lv / nrm;
}

// ---------------------------------------------------------------- launch
extern "C" void kernel_launch(void* const* d_in, const int* in_sizes, int n_in,
                              void* d_out, int out_size, void* d_ws, size_t ws_size,
                              hipStream_t stream) {
  const int* item_seq = (const int*)d_in[0];
  const int* action_seq = (const int*)d_in[1];
  const int* time_diff = (const int*)d_in[2];
  const int* mask = (const int*)d_in[3];
  const int* u_cv = (const int*)d_in[4];
  const int* u_cl = (const int*)d_in[5];
  const float* u_num = (const float*)d_in[6];
  const int* i_cv = (const int*)d_in[7];
  const int* i_cl = (const int*)d_in[8];
  const float* i_num = (const float*)d_in[9];
  const float* item_t = (const float*)d_in[10];
  const float* act_t = (const float*)d_in[11];
  const float* time_t = (const float*)d_in[12];
  const float* cat_t = (const float*)d_in[13];
  const float* num_W = (const float*)d_in[14];
  const float* gtok = (const float*)d_in[15];
  const float* ln1_g = (const float*)d_in[16];
  const float* ln1_b = (const float*)d_in[17];
  const float* qkv_w = (const float*)d_in[18];
  const float* qkv_b = (const float*)d_in[19];
  const float* out_w = (const float*)d_in[20];
  const float* out_b = (const float*)d_in[21];
  const float* w1 = (const float*)d_in[22];
  const float* b1 = (const float*)d_in[23];
  const float* w2 = (const float*)d_in[24];
  const float* b2 = (const float*)d_in[25];
  const float* ln2_g = (const float*)d_in[26];
  const float* ln2_b = (const float*)d_in[27];
  const float* bott_w = (const float*)d_in[28];
  const float* bott_b = (const float*)d_in[29];
  const float* cls_w = (const float*)d_in[30];
  const float* cls_b = (const float*)d_in[31];

  // workspace layout (bytes)
  const size_t off_x   = 0;                    // TTOK*128 f32  = 33,947,648
  const size_t off_src = 33947648;             // TTOK*128 bf16 = 16,973,824 (attn out)
  const size_t off_big = 50921472;             // TTOK*512 bf16 = 67,895,296 (qkv / h1)
  const size_t off_wT  = 118816768;            // 786,432 elems bf16
  const size_t need    = 120389632;
  if (ws_size < need) {
    fprintf(stderr, "kernel_launch: ws_size %zu < needed %zu\n", ws_size, need);
    return;
  }
  char* ws = (char*)d_ws;
  float* x   = (float*)(ws + off_x);
  u16* src   = (u16*)(ws + off_src);
  u16* big   = (u16*)(ws + off_big);
  u16* wT    = (u16*)(ws + off_wT);
  u16* qkvT  = wT;                 // [4][384][128]
  u16* outT  = wT + 196608;        // [4][128][128]
  u16* w1T   = wT + 262144;        // [4][512][128]
  u16* w2T   = wT + 524288;        // [4][128][512]

  k_transpose<<<(4 * 128 * 384 + 255) / 256, 256, 0, stream>>>(qkv_w, qkvT, 4, 128, 384);
  k_transpose<<<(4 * 128 * 128 + 255) / 256, 256, 0, stream>>>(out_w, outT, 4, 128, 128);
  k_transpose<<<(4 * 128 * 512 + 255) / 256, 256, 0, stream>>>(w1, w1T, 4, 128, 512);
  k_transpose<<<(4 * 512 * 128 + 255) / 256, 256, 0, stream>>>(w2, w2T, 4, 512, 128);

  k_build<<<dim3(NPOS, BATCH), 128, 0, stream>>>(
      item_seq, action_seq, time_diff, u_cv, u_cl, u_num, i_cv, i_cl, i_num,
      item_t, act_t, time_t, cat_t, num_W, gtok, x);

  const int rt = TTOK / 128;  // 518
  for (int dd = 0; dd < DEPTH; ++dd) {
    // QKV (LN1 fused, q cols pre-scaled by 0.25)
    k_gemm2<0, false, true, true><<<dim3(rt, 3), 256, 0, stream>>>(
        x, qkvT + dd * 49152, ln1_g + dd * HD, ln1_b + dd * HD, qkv_b + dd * 384, big, 128, 384);
    k_attn<<<dim3(NHEAD, BATCH), 256, 0, stream>>>(big, mask, src);
    // proj (+residual into x)
    k_gemm2<0, true, false, false><<<dim3(rt, 1), 256, 0, stream>>>(
        src, outT + dd * 16384, nullptr, nullptr, out_b + dd * HD, x, 128, 128);
    // MLP1 (LN2 fused, gelu)
    k_gemm2<1, false, false, true><<<dim3(rt, 4), 256, 0, stream>>>(
        x, w1T + dd * 65536, ln2_g + dd * HD, ln2_b + dd * HD, b1 + dd * FF, big, 128, 512);
    // MLP2 (+residual into x), K=512
    k_gemm2<0, true, false, false><<<dim3(rt, 1), 256, 0, stream>>>(
        big, w2T + dd * 65536, nullptr, nullptr, b2 + dd * HD, x, 512, 128);
  }

  k_head<<<BATCH, 128, 0, stream>>>(x, bott_w, bott_b, cls_w, cls_b, (float*)d_out);
}

// Round 7
// 944.940 us; speedup vs baseline: 1.3558x; 1.3558x over previous
//
#include <hip/hip_runtime.h>
#include <cstdio>

// Problem constants
#define BATCH 256
#define SEQL 256
#define NPOS 259            // 3 + SEQL
#define TTOK (BATCH*NPOS)   // 66304 = 518 * 128
#define HD 128
#define NHEAD 8
#define FF 512
#define DEPTH 4
#define CVOC 50001

typedef unsigned short u16;
typedef unsigned int u32;
typedef __bf16 bf16x8 __attribute__((ext_vector_type(8)));
typedef float f32x4 __attribute__((ext_vector_type(4)));
typedef float f32x16 __attribute__((ext_vector_type(16)));

typedef const __attribute__((address_space(1))) u32 gas_u32;
typedef __attribute__((address_space(3))) u32 las_u32;
#define GLOAD16(gptr, lptr) \
  __builtin_amdgcn_global_load_lds((gas_u32*)(gptr), (las_u32*)(lptr), 16, 0, 0)

__device__ __forceinline__ u16 f2bf(float f) {
  u32 i = __float_as_uint(f);
  u32 r = (i + 0x7FFFu + ((i >> 16) & 1u)) >> 16;   // RNE
  return (u16)r;
}

// ---------------------------------------------------------------- transpose + downcast
// in (fp32): [D][K][N] -> out (bf16): [D][N][K]
__global__ void k_transpose(const float* __restrict__ in, u16* __restrict__ out,
                            int D, int K, int N) {
  int idx = blockIdx.x * 256 + threadIdx.x;
  int total = D * K * N;
  if (idx >= total) return;
  int k = idx % K; int rem = idx / K; int n = rem % N; int d = rem / N;
  out[idx] = f2bf(in[(d * K + k) * N + n]);
}

// ---------------------------------------------------------------- build x
__global__ __launch_bounds__(128)
void k_build(const int* __restrict__ item_seq, const int* __restrict__ act_seq,
             const int* __restrict__ tdiff,
             const int* __restrict__ ucv, const int* __restrict__ ucl, const float* __restrict__ unum,
             const int* __restrict__ icv, const int* __restrict__ icl, const float* __restrict__ inum,
             const float* __restrict__ item_t, const float* __restrict__ act_t,
             const float* __restrict__ time_t, const float* __restrict__ cat_t,
             const float* __restrict__ numW, const float* __restrict__ gtok,
             float* __restrict__ x) {
  int pos = blockIdx.x, b = blockIdx.y, h = threadIdx.x;
  float v;
  if (pos == 0) {
    v = gtok[h];
  } else if (pos <= 2) {
    const int* cv = (pos == 1) ? ucv : icv;
    const int* cl = (pos == 1) ? ucl : icl;
    const float* nm = (pos == 1) ? unum : inum;
    float acc = 0.f;
    for (int f = 0; f < 8; ++f) {
      float s = 0.f;
      for (int k = 0; k < 8; ++k) {
        int idx = cv[(b * 8 + f) * 8 + k];
        s += cat_t[((size_t)f * CVOC + idx) * HD + h];
      }
      acc += s / (float)cl[b * 8 + f];
    }
    for (int f = 0; f < 4; ++f)
      for (int d = 0; d < 32; ++d)
        acc += nm[(b * 4 + f) * 32 + d] * numW[(f * 32 + d) * HD + h];
    v = acc * (1.f / 12.f);
  } else {
    int l = pos - 3;
    v = item_t[(size_t)item_seq[b * SEQL + l] * HD + h]
      + act_t[(size_t)act_seq[b * SEQL + l] * HD + h]
      + time_t[(size_t)tdiff[b * SEQL + l] * HD + h];
  }
  x[((size_t)b * NPOS + pos) * HD + h] = v;
}

// ---------------------------------------------------------------- layernorm
__global__ __launch_bounds__(256)
void k_ln(const float* __restrict__ x, const float* __restrict__ g,
          const float* __restrict__ be, u16* __restrict__ out) {
  int t = blockIdx.x * 4 + (threadIdx.x >> 6);
  int lane = threadIdx.x & 63;
  const float* xr = x + (size_t)t * HD;
  float a = xr[lane], c = xr[lane + 64];
  float s = a + c, s2 = a * a + c * c;
  #pragma unroll
  for (int o = 32; o; o >>= 1) { s += __shfl_xor(s, o); s2 += __shfl_xor(s2, o); }
  float mean = s * (1.f / HD);
  float var = s2 * (1.f / HD) - mean * mean;
  float rstd = rsqrtf(var + 1e-5f);
  out[(size_t)t * HD + lane]      = f2bf((a - mean) * rstd * g[lane] + be[lane]);
  out[(size_t)t * HD + lane + 64] = f2bf((c - mean) * rstd * g[lane + 64] + be[lane + 64]);
}

// ---------------------------------------------------------------- GEMM (MFMA, m97 structure, BK=32)
// Y[T x N] = act(X @ W + bias); WT[N][K] bf16. Tile 128x128, 4 waves 2x2.
template <int ACT, bool RESID>
__global__ __launch_bounds__(256)
void k_gemm(const u16* __restrict__ X, const u16* __restrict__ WT,
            const float* __restrict__ bias, void* __restrict__ outp,
            int K, int N) {
  __shared__ __align__(16) u16 lA[128 * 32];
  __shared__ __align__(16) u16 lB[128 * 32];
  const int tid = threadIdx.x;
  const int wave = tid >> 6, lane = tid & 63;
  const int row0 = blockIdx.x * 128;
  const int n0 = blockIdx.y * 128;
  const int wr = (wave >> 1) * 64, wc = (wave & 1) * 64;
  const int sr = lane >> 2;
  const int sc = ((lane & 3) ^ ((lane >> 3) & 3)) << 3;
  const u16* gA0 = X  + (size_t)(row0 + wave * 16 + sr) * K + sc;
  const u16* gA1 = X  + (size_t)(row0 + 64 + wave * 16 + sr) * K + sc;
  const u16* gB0 = WT + (size_t)(n0 + wave * 16 + sr) * K + sc;
  const u16* gB1 = WT + (size_t)(n0 + 64 + wave * 16 + sr) * K + sc;
  u16* lA0 = &lA[wave * 512];
  u16* lA1 = &lA[2048 + wave * 512];
  u16* lB0 = &lB[wave * 512];
  u16* lB1 = &lB[2048 + wave * 512];
  const int q = lane & 15;
  const int cg = lane >> 4;
  const int rdoff = ((cg ^ ((q >> 1) & 3)) << 3);
  f32x4 acc[4][4] = {};
  for (int k0 = 0; k0 < K; k0 += 32) {
    __syncthreads();
    GLOAD16(gA0 + k0, lA0);
    GLOAD16(gA1 + k0, lA1);
    GLOAD16(gB0 + k0, lB0);
    GLOAD16(gB1 + k0, lB1);
    __syncthreads();
    bf16x8 af[4], bf[4];
    #pragma unroll
    for (int i = 0; i < 4; ++i)
      af[i] = *(const bf16x8*)&lA[(wr + i * 16 + q) * 32 + rdoff];
    #pragma unroll
    for (int j = 0; j < 4; ++j)
      bf[j] = *(const bf16x8*)&lB[(wc + j * 16 + q) * 32 + rdoff];
    #pragma unroll
    for (int i = 0; i < 4; ++i)
      #pragma unroll
      for (int j = 0; j < 4; ++j)
        acc[i][j] = __builtin_amdgcn_mfma_f32_16x16x32_bf16(af[i], bf[j], acc[i][j], 0, 0, 0);
  }
  const int rg4 = cg * 4;
  #pragma unroll
  for (int i = 0; i < 4; ++i) {
    #pragma unroll
    for (int j = 0; j < 4; ++j) {
      int col = n0 + wc + j * 16 + q;
      float bv = bias[col];
      #pragma unroll
      for (int jj = 0; jj < 4; ++jj) {
        int row = row0 + wr + i * 16 + rg4 + jj;
        float v = acc[i][j][jj] + bv;
        if (ACT == 1) v = 0.5f * v * (1.f + erff(v * 0.70710678118654752f));
        if (RESID) ((float*)outp)[(size_t)row * N + col] += v;
        else ((u16*)outp)[(size_t)row * N + col] = f2bf(v);
      }
    }
  }
}

// ---------------------------------------------------------------- QKV GEMM (special epilogue)
// Writes q (scaled 0.25) to qbuf[T][128]; K frag-linear: Kfrag[(b*8+h)*4608 +
// (r>>5)*512 + (d>>3)*256 + (r&31)*8 + (d&7)]; V transposed: Vtr[(b*8+h)*4608 + d*288 + r].
__global__ __launch_bounds__(256)
void k_gemmqkv(const u16* __restrict__ X, const u16* __restrict__ WT,
               const float* __restrict__ bias, u16* __restrict__ qbuf,
               u16* __restrict__ kfr, u16* __restrict__ vtr) {
  const int K = 128, N = 384;
  __shared__ __align__(16) u16 lA[128 * 32];
  __shared__ __align__(16) u16 lB[128 * 32];
  const int tid = threadIdx.x;
  const int wave = tid >> 6, lane = tid & 63;
  const int row0 = blockIdx.x * 128;
  const int n0 = blockIdx.y * 128;
  const int wr = (wave >> 1) * 64, wc = (wave & 1) * 64;
  const int sr = lane >> 2;
  const int sc = ((lane & 3) ^ ((lane >> 3) & 3)) << 3;
  const u16* gA0 = X  + (size_t)(row0 + wave * 16 + sr) * K + sc;
  const u16* gA1 = X  + (size_t)(row0 + 64 + wave * 16 + sr) * K + sc;
  const u16* gB0 = WT + (size_t)(n0 + wave * 16 + sr) * K + sc;
  const u16* gB1 = WT + (size_t)(n0 + 64 + wave * 16 + sr) * K + sc;
  u16* lA0 = &lA[wave * 512];
  u16* lA1 = &lA[2048 + wave * 512];
  u16* lB0 = &lB[wave * 512];
  u16* lB1 = &lB[2048 + wave * 512];
  const int q = lane & 15;
  const int cg = lane >> 4;
  const int rdoff = ((cg ^ ((q >> 1) & 3)) << 3);
  f32x4 acc[4][4] = {};
  for (int k0 = 0; k0 < K; k0 += 32) {
    __syncthreads();
    GLOAD16(gA0 + k0, lA0);
    GLOAD16(gA1 + k0, lA1);
    GLOAD16(gB0 + k0, lB0);
    GLOAD16(gB1 + k0, lB1);
    __syncthreads();
    bf16x8 af[4], bf[4];
    #pragma unroll
    for (int i = 0; i < 4; ++i)
      af[i] = *(const bf16x8*)&lA[(wr + i * 16 + q) * 32 + rdoff];
    #pragma unroll
    for (int j = 0; j < 4; ++j)
      bf[j] = *(const bf16x8*)&lB[(wc + j * 16 + q) * 32 + rdoff];
    #pragma unroll
    for (int i = 0; i < 4; ++i)
      #pragma unroll
      for (int j = 0; j < 4; ++j)
        acc[i][j] = __builtin_amdgcn_mfma_f32_16x16x32_bf16(af[i], bf[j], acc[i][j], 0, 0, 0);
  }
  const int rg4 = cg * 4;
  #pragma unroll
  for (int i = 0; i < 4; ++i) {
    #pragma unroll
    for (int j = 0; j < 4; ++j) {
      int col = n0 + wc + j * 16 + q;
      float bv = bias[col];
      #pragma unroll
      for (int jj = 0; jj < 4; ++jj) {
        int row = row0 + wr + i * 16 + rg4 + jj;
        float v = acc[i][j][jj] + bv;
        if (col < 128) {
          qbuf[(size_t)row * 128 + col] = f2bf(v * 0.25f);
        } else {
          u32 b = (u32)row / NPOS;
          u32 r = (u32)row - b * NPOS;
          int d = col & 15;
          if (col < 256) {
            int h2 = (col - 128) >> 4;
            kfr[((size_t)b * 8 + h2) * 4608 + (r >> 5) * 512 + (d >> 3) * 256 + (r & 31) * 8 + (d & 7)] = f2bf(v);
          } else {
            int h2 = (col - 256) >> 4;
            vtr[((size_t)b * 8 + h2) * 4608 + d * 288 + r] = f2bf(v);
          }
        }
      }
    }
  }
}

// ---------------------------------------------------------------- attention (register-direct)
// grid (NHEAD, BATCH), 256 threads = 4 waves. No LDS staging: K frag-linear and
// V transposed are read directly from global (L2-resident, 9.2 KB each per head).
__global__ __launch_bounds__(256)
void k_attn(const u16* __restrict__ qbuf, const u16* __restrict__ kfr,
            const u16* __restrict__ vtr, const int* __restrict__ mask,
            u16* __restrict__ out) {
  int h = blockIdx.x, b = blockIdx.y;
  __shared__ int part[4];
  const int tid = threadIdx.x;
  int mv = (mask[b * SEQL + tid] != 0) ? 1 : 0;
  #pragma unroll
  for (int o = 32; o; o >>= 1) mv += __shfl_xor(mv, o);
  if ((tid & 63) == 0) part[tid >> 6] = mv;
  __syncthreads();
  const int nvalid = part[0] + part[1] + part[2] + part[3] + 3;
  const int ktiles = (nvalid + 31) >> 5;
  const u16* kfb = kfr + ((size_t)b * 8 + h) * 4608;
  const u16* vtb = vtr + ((size_t)b * 8 + h) * 4608;
  const int wave = tid >> 6, lane = tid & 63;
  const int q5 = lane & 31, hi = lane >> 5;
  const f32x16 zf = {};
  for (int qt = wave; qt < 9; qt += 4) {
    int qrow = qt * 32 + q5;
    int qr = (qrow < NPOS) ? qrow : (NPOS - 1);
    bf16x8 qf = *(const bf16x8*)&qbuf[(size_t)(b * NPOS + qr) * 128 + hi * 8];
    float m = -1e30f, l = 0.f;
    f32x16 acc = {};
    for (int kt = 0; kt < ktiles; ++kt) {
      bf16x8 kf = *(const bf16x8*)&kfb[kt * 512 + lane * 8];
      f32x16 s4 = __builtin_amdgcn_mfma_f32_32x32x16_bf16(kf, qf, zf, 0, 0, 0);
      float p[16];
      float tmax = -1e30f;
      #pragma unroll
      for (int r = 0; r < 16; ++r) {
        int kr = kt * 32 + (r & 3) + 8 * (r >> 2) + 4 * hi;
        float v = (kr < nvalid) ? s4[r] : -1e30f;
        p[r] = v;
        tmax = fmaxf(tmax, v);
      }
      tmax = fmaxf(tmax, __shfl_xor(tmax, 32));
      float mnew = fmaxf(m, tmax);
      float fac = __expf(m - mnew);
      float tsum = 0.f;
      #pragma unroll
      for (int r = 0; r < 16; ++r) { p[r] = __expf(p[r] - mnew); tsum += p[r]; }
      tsum += __shfl_xor(tsum, 32);
      l = l * fac + tsum;
      m = mnew;
      #pragma unroll
      for (int r = 0; r < 8; ++r) acc[r] *= fac;   // regs 8-15 stay 0
      u32 w[8], xw[8];
      #pragma unroll
      for (int i = 0; i < 8; ++i)
        asm("v_cvt_pk_bf16_f32 %0, %1, %2" : "=v"(w[i]) : "v"(p[2 * i]), "v"(p[2 * i + 1]));
      #pragma unroll
      for (int i = 0; i < 8; ++i) xw[i] = (u32)__shfl_xor((int)w[i], 32);
      union { u32 u[4]; bf16x8 v; } f1, f2;
      if (hi) {
        f1.u[0] = xw[2]; f1.u[1] = xw[3]; f1.u[2] = w[2]; f1.u[3] = w[3];
        f2.u[0] = xw[6]; f2.u[1] = xw[7]; f2.u[2] = w[6]; f2.u[3] = w[7];
      } else {
        f1.u[0] = w[0]; f1.u[1] = w[1]; f1.u[2] = xw[0]; f1.u[3] = xw[1];
        f2.u[0] = w[4]; f2.u[1] = w[5]; f2.u[2] = xw[4]; f2.u[3] = xw[5];
      }
      bf16x8 vf0 = {}, vf1 = {};
      if (q5 < 16) {
        vf0 = *(const bf16x8*)&vtb[q5 * 288 + kt * 32 + hi * 8];
        vf1 = *(const bf16x8*)&vtb[q5 * 288 + kt * 32 + 16 + hi * 8];
      }
      acc = __builtin_amdgcn_mfma_f32_32x32x16_bf16(vf0, f1.v, acc, 0, 0, 0);
      acc = __builtin_amdgcn_mfma_f32_32x32x16_bf16(vf1, f2.v, acc, 0, 0, 0);
    }
    if (qrow < NPOS) {
      float linv = 1.f / l;
      u16* op = &out[((size_t)(b * NPOS + qrow)) * HD + h * 16];
      u32 w0 = (u32)f2bf(acc[0] * linv) | ((u32)f2bf(acc[1] * linv) << 16);
      u32 w1 = (u32)f2bf(acc[2] * linv) | ((u32)f2bf(acc[3] * linv) << 16);
      u32 w2 = (u32)f2bf(acc[4] * linv) | ((u32)f2bf(acc[5] * linv) << 16);
      u32 w3 = (u32)f2bf(acc[6] * linv) | ((u32)f2bf(acc[7] * linv) << 16);
      *(uint2*)&op[4 * hi] = make_uint2(w0, w1);
      *(uint2*)&op[8 + 4 * hi] = make_uint2(w2, w3);
    }
  }
}

// ---------------------------------------------------------------- head
__global__ __launch_bounds__(128)
void k_head(const float* __restrict__ x, const float* __restrict__ bw,
            const float* __restrict__ bb, const float* __restrict__ cw,
            const float* __restrict__ cb, float* __restrict__ dout) {
  int b = blockIdx.x, n = threadIdx.x;
  __shared__ float lat[HD];
  __shared__ float redp[2], redss[2];
  float lv = x[((size_t)b * NPOS) * HD + n];
  lat[n] = lv;
  __syncthreads();
  float t = 0.f;
  for (int k = 0; k < HD; ++k) t += lat[k] * bw[k * HD + n];
  t += bb[n];
  t = fmaxf(t, 0.f);
  float p = t * cw[n];
  float ss = lv * lv;
  #pragma unroll
  for (int o = 32; o; o >>= 1) { p += __shfl_xor(p, o); ss += __shfl_xor(ss, o); }
  if ((n & 63) == 0) { redp[n >> 6] = p; redss[n >> 6] = ss; }
  __syncthreads();
  float psum = redp[0] + redp[1];
  float ssum = redss[0] + redss[1];
  if (n == 0) dout[b] = psum + cb[0];
  float nrm = fmaxf(sqrtf(ssum), 1e-12f);
  dout[256 + (size_t)b * HD + n] = lv / nrm;
}

// ---------------------------------------------------------------- launch
extern "C" void kernel_launch(void* const* d_in, const int* in_sizes, int n_in,
                              void* d_out, int out_size, void* d_ws, size_t ws_size,
                              hipStream_t stream) {
  const int* item_seq = (const int*)d_in[0];
  const int* action_seq = (const int*)d_in[1];
  const int* time_diff = (const int*)d_in[2];
  const int* mask = (const int*)d_in[3];
  const int* u_cv = (const int*)d_in[4];
  const int* u_cl = (const int*)d_in[5];
  const float* u_num = (const float*)d_in[6];
  const int* i_cv = (const int*)d_in[7];
  const int* i_cl = (const int*)d_in[8];
  const float* i_num = (const float*)d_in[9];
  const float* item_t = (const float*)d_in[10];
  const float* act_t = (const float*)d_in[11];
  const float* time_t = (const float*)d_in[12];
  const float* cat_t = (const float*)d_in[13];
  const float* num_W = (const float*)d_in[14];
  const float* gtok = (const float*)d_in[15];
  const float* ln1_g = (const float*)d_in[16];
  const float* ln1_b = (const float*)d_in[17];
  const float* qkv_w = (const float*)d_in[18];
  const float* qkv_b = (const float*)d_in[19];
  const float* out_w = (const float*)d_in[20];
  const float* out_b = (const float*)d_in[21];
  const float* w1 = (const float*)d_in[22];
  const float* b1 = (const float*)d_in[23];
  const float* w2 = (const float*)d_in[24];
  const float* b2 = (const float*)d_in[25];
  const float* ln2_g = (const float*)d_in[26];
  const float* ln2_b = (const float*)d_in[27];
  const float* bott_w = (const float*)d_in[28];
  const float* bott_b = (const float*)d_in[29];
  const float* cls_w = (const float*)d_in[30];
  const float* cls_b = (const float*)d_in[31];

  // workspace layout (bytes)
  const size_t off_x    = 0;                      // TTOK*128 f32  = 33,947,648
  const size_t off_src  = 33947648;               // TTOK*128 bf16 = 16,973,824 (LN out / attn out)
  const size_t off_q    = 50921472;               // TTOK*128 bf16 = 16,973,824
  const size_t off_kf   = 67895296;               // 256*8*4608 bf16 = 18,874,368
  const size_t off_vt   = 86769664;               // 256*8*4608 bf16 = 18,874,368
  const size_t off_big  = 105644032;              // TTOK*512 bf16 = 67,895,296
  const size_t off_wT   = 173539328;              // 786,432 elems bf16
  const size_t need     = 175112192;
  if (ws_size < need) {
    fprintf(stderr, "kernel_launch: ws_size %zu < needed %zu\n", ws_size, need);
    return;
  }
  char* ws = (char*)d_ws;
  float* x   = (float*)(ws + off_x);
  u16* src   = (u16*)(ws + off_src);
  u16* qbuf  = (u16*)(ws + off_q);
  u16* kfr   = (u16*)(ws + off_kf);
  u16* vtr   = (u16*)(ws + off_vt);
  u16* big   = (u16*)(ws + off_big);
  u16* wT    = (u16*)(ws + off_wT);
  u16* qkvT  = wT;                 // [4][384][128]
  u16* outT  = wT + 196608;        // [4][128][128]
  u16* w1T   = wT + 262144;        // [4][512][128]
  u16* w2T   = wT + 524288;        // [4][128][512]

  k_transpose<<<(4 * 128 * 384 + 255) / 256, 256, 0, stream>>>(qkv_w, qkvT, 4, 128, 384);
  k_transpose<<<(4 * 128 * 128 + 255) / 256, 256, 0, stream>>>(out_w, outT, 4, 128, 128);
  k_transpose<<<(4 * 128 * 512 + 255) / 256, 256, 0, stream>>>(w1, w1T, 4, 128, 512);
  k_transpose<<<(4 * 512 * 128 + 255) / 256, 256, 0, stream>>>(w2, w2T, 4, 512, 128);

  k_build<<<dim3(NPOS, BATCH), 128, 0, stream>>>(
      item_seq, action_seq, time_diff, u_cv, u_cl, u_num, i_cv, i_cl, i_num,
      item_t, act_t, time_t, cat_t, num_W, gtok, x);

  const int rt = TTOK / 128;  // 518
  for (int dd = 0; dd < DEPTH; ++dd) {
    k_ln<<<TTOK / 4, 256, 0, stream>>>(x, ln1_g + dd * HD, ln1_b + dd * HD, src);
    k_gemmqkv<<<dim3(rt, 3), 256, 0, stream>>>(src, qkvT + dd * 49152, qkv_b + dd * 384, qbuf, kfr, vtr);
    k_attn<<<dim3(NHEAD, BATCH), 256, 0, stream>>>(qbuf, kfr, vtr, mask, src);
    k_gemm<0, true><<<dim3(rt, 1), 256, 0, stream>>>(src, outT + dd * 16384, out_b + dd * HD, x, 128, 128);
    k_ln<<<TTOK / 4, 256, 0, stream>>>(x, ln2_g + dd * HD, ln2_b + dd * HD, src);
    k_gemm<1, false><<<dim3(rt, 4), 256, 0, stream>>>(src, w1T + dd * 65536, b1 + dd * FF, big, 128, 512);
    k_gemm<0, true><<<dim3(rt, 1), 256, 0, stream>>>(big, w2T + dd * 65536, b2 + dd * HD, x, 512, 128);
  }

  k_head<<<BATCH, 128, 0, stream>>>(x, bott_w, bott_b, cls_w, cls_b, (float*)d_out);
}

// Round 8
// 840.872 us; speedup vs baseline: 1.5236x; 1.1238x over previous
//
#include <hip/hip_runtime.h>
#include <cstdio>

// Problem constants
#define BATCH 256
#define SEQL 256
#define NPOS 259            // 3 + SEQL
#define TTOK (BATCH*NPOS)   // 66304 = 518 * 128
#define HD 128
#define NHEAD 8
#define FF 512
#define DEPTH 4
#define CVOC 50001

typedef unsigned short u16;
typedef unsigned int u32;
typedef __bf16 bf16x8 __attribute__((ext_vector_type(8)));
typedef float f32x4 __attribute__((ext_vector_type(4)));
typedef float f32x16 __attribute__((ext_vector_type(16)));

typedef const __attribute__((address_space(1))) u32 gas_u32;
typedef __attribute__((address_space(3))) u32 las_u32;
#define GLOAD16(gptr, lptr) \
  __builtin_amdgcn_global_load_lds((gas_u32*)(gptr), (las_u32*)(lptr), 16, 0, 0)

__device__ __forceinline__ u16 f2bf(float f) {
  u32 i = __float_as_uint(f);
  u32 r = (i + 0x7FFFu + ((i >> 16) & 1u)) >> 16;   // RNE
  return (u16)r;
}

// ---------------------------------------------------------------- transpose + downcast
// in (fp32): [D][K][N] -> out (bf16): [D][N][K]
__global__ void k_transpose(const float* __restrict__ in, u16* __restrict__ out,
                            int D, int K, int N) {
  int idx = blockIdx.x * 256 + threadIdx.x;
  int total = D * K * N;
  if (idx >= total) return;
  int k = idx % K; int rem = idx / K; int n = rem % N; int d = rem / N;
  out[idx] = f2bf(in[(d * K + k) * N + n]);
}

// ---------------------------------------------------------------- build x
__global__ __launch_bounds__(128)
void k_build(const int* __restrict__ item_seq, const int* __restrict__ act_seq,
             const int* __restrict__ tdiff,
             const int* __restrict__ ucv, const int* __restrict__ ucl, const float* __restrict__ unum,
             const int* __restrict__ icv, const int* __restrict__ icl, const float* __restrict__ inum,
             const float* __restrict__ item_t, const float* __restrict__ act_t,
             const float* __restrict__ time_t, const float* __restrict__ cat_t,
             const float* __restrict__ numW, const float* __restrict__ gtok,
             float* __restrict__ x) {
  int pos = blockIdx.x, b = blockIdx.y, h = threadIdx.x;
  float v;
  if (pos == 0) {
    v = gtok[h];
  } else if (pos <= 2) {
    const int* cv = (pos == 1) ? ucv : icv;
    const int* cl = (pos == 1) ? ucl : icl;
    const float* nm = (pos == 1) ? unum : inum;
    float acc = 0.f;
    for (int f = 0; f < 8; ++f) {
      float s = 0.f;
      for (int k = 0; k < 8; ++k) {
        int idx = cv[(b * 8 + f) * 8 + k];
        s += cat_t[((size_t)f * CVOC + idx) * HD + h];
      }
      acc += s / (float)cl[b * 8 + f];
    }
    for (int f = 0; f < 4; ++f)
      for (int d = 0; d < 32; ++d)
        acc += nm[(b * 4 + f) * 32 + d] * numW[(f * 32 + d) * HD + h];
    v = acc * (1.f / 12.f);
  } else {
    int l = pos - 3;
    v = item_t[(size_t)item_seq[b * SEQL + l] * HD + h]
      + act_t[(size_t)act_seq[b * SEQL + l] * HD + h]
      + time_t[(size_t)tdiff[b * SEQL + l] * HD + h];
  }
  x[((size_t)b * NPOS + pos) * HD + h] = v;
}

// ---------------------------------------------------------------- layernorm (layer-0 LN1 only)
__global__ __launch_bounds__(256)
void k_ln(const float* __restrict__ x, const float* __restrict__ g,
          const float* __restrict__ be, u16* __restrict__ out) {
  int t = blockIdx.x * 4 + (threadIdx.x >> 6);
  int lane = threadIdx.x & 63;
  const float* xr = x + (size_t)t * HD;
  float a = xr[lane], c = xr[lane + 64];
  float s = a + c, s2 = a * a + c * c;
  #pragma unroll
  for (int o = 32; o; o >>= 1) { s += __shfl_xor(s, o); s2 += __shfl_xor(s2, o); }
  float mean = s * (1.f / HD);
  float var = s2 * (1.f / HD) - mean * mean;
  float rstd = rsqrtf(var + 1e-5f);
  out[(size_t)t * HD + lane]      = f2bf((a - mean) * rstd * g[lane] + be[lane]);
  out[(size_t)t * HD + lane + 64] = f2bf((c - mean) * rstd * g[lane + 64] + be[lane + 64]);
}

// ---------------------------------------------------------------- GEMM (MFMA, m97 structure, BK=32)
// Y[T x N] = act(X @ W + bias); WT[N][K] bf16. Tile 128x128, 4 waves 2x2.
// ACT 1 = exact gelu. QS: cols<128 scaled by 0.25 (attention SCALE folded into q).
template <int ACT, bool QS>
__global__ __launch_bounds__(256)
void k_gemm(const u16* __restrict__ X, const u16* __restrict__ WT,
            const float* __restrict__ bias, u16* __restrict__ outp,
            int K, int N) {
  __shared__ __align__(16) u16 lA[128 * 32];
  __shared__ __align__(16) u16 lB[128 * 32];
  const int tid = threadIdx.x;
  const int wave = tid >> 6, lane = tid & 63;
  const int row0 = blockIdx.x * 128;
  const int n0 = blockIdx.y * 128;
  const int wr = (wave >> 1) * 64, wc = (wave & 1) * 64;
  const int sr = lane >> 2;
  const int sc = ((lane & 3) ^ ((lane >> 3) & 3)) << 3;
  const u16* gA0 = X  + (size_t)(row0 + wave * 16 + sr) * K + sc;
  const u16* gA1 = X  + (size_t)(row0 + 64 + wave * 16 + sr) * K + sc;
  const u16* gB0 = WT + (size_t)(n0 + wave * 16 + sr) * K + sc;
  const u16* gB1 = WT + (size_t)(n0 + 64 + wave * 16 + sr) * K + sc;
  u16* lA0 = &lA[wave * 512];
  u16* lA1 = &lA[2048 + wave * 512];
  u16* lB0 = &lB[wave * 512];
  u16* lB1 = &lB[2048 + wave * 512];
  const int q = lane & 15;
  const int cg = lane >> 4;
  const int rdoff = ((cg ^ ((q >> 1) & 3)) << 3);
  f32x4 acc[4][4] = {};
  for (int k0 = 0; k0 < K; k0 += 32) {
    __syncthreads();
    GLOAD16(gA0 + k0, lA0);
    GLOAD16(gA1 + k0, lA1);
    GLOAD16(gB0 + k0, lB0);
    GLOAD16(gB1 + k0, lB1);
    __syncthreads();
    bf16x8 af[4], bf[4];
    #pragma unroll
    for (int i = 0; i < 4; ++i)
      af[i] = *(const bf16x8*)&lA[(wr + i * 16 + q) * 32 + rdoff];
    #pragma unroll
    for (int j = 0; j < 4; ++j)
      bf[j] = *(const bf16x8*)&lB[(wc + j * 16 + q) * 32 + rdoff];
    #pragma unroll
    for (int i = 0; i < 4; ++i)
      #pragma unroll
      for (int j = 0; j < 4; ++j)
        acc[i][j] = __builtin_amdgcn_mfma_f32_16x16x32_bf16(af[i], bf[j], acc[i][j], 0, 0, 0);
  }
  const int rg4 = cg * 4;
  #pragma unroll
  for (int i = 0; i < 4; ++i) {
    #pragma unroll
    for (int j = 0; j < 4; ++j) {
      int col = n0 + wc + j * 16 + q;
      float bv = bias[col];
      float scl = (QS && col < 128) ? 0.25f : 1.f;
      #pragma unroll
      for (int jj = 0; jj < 4; ++jj) {
        int row = row0 + wr + i * 16 + rg4 + jj;
        float v = acc[i][j][jj] + bv;
        if (ACT == 1) v = 0.5f * v * (1.f + erff(v * 0.70710678118654752f));
        if (QS) v *= scl;
        outp[(size_t)row * N + col] = f2bf(v);
      }
    }
  }
}

// ---------------------------------------------------------------- residual GEMM + fused LN (N=128)
// xio[T][128] fp32: xnew = xio + X@W + bias (written back).
// srcout[T][128] bf16: layernorm(xnew; g,be). Block tile 128x128 covers all cols,
// so LN row-stats are computed in-block: per-thread partials -> q-lane butterfly
// (64-col half) -> 2KB LDS exchange between column-half waves -> stats.
__global__ __launch_bounds__(256)
void k_gemm_ln(const u16* __restrict__ X, const u16* __restrict__ WT,
               const float* __restrict__ bias, float* __restrict__ xio,
               const float* __restrict__ g, const float* __restrict__ be,
               u16* __restrict__ srcout, int K) {
  __shared__ __align__(16) u16 lA[128 * 32];
  __shared__ __align__(16) u16 lB[128 * 32];
  __shared__ float part[128][2][2];
  const int tid = threadIdx.x;
  const int wave = tid >> 6, lane = tid & 63;
  const int row0 = blockIdx.x * 128;
  const int wr = (wave >> 1) * 64, wc = (wave & 1) * 64;
  const int whalf = wave & 1;
  const int sr = lane >> 2;
  const int sc = ((lane & 3) ^ ((lane >> 3) & 3)) << 3;
  const u16* gA0 = X  + (size_t)(row0 + wave * 16 + sr) * K + sc;
  const u16* gA1 = X  + (size_t)(row0 + 64 + wave * 16 + sr) * K + sc;
  const u16* gB0 = WT + (size_t)(wave * 16 + sr) * K + sc;
  const u16* gB1 = WT + (size_t)(64 + wave * 16 + sr) * K + sc;
  u16* lA0 = &lA[wave * 512];
  u16* lA1 = &lA[2048 + wave * 512];
  u16* lB0 = &lB[wave * 512];
  u16* lB1 = &lB[2048 + wave * 512];
  const int q = lane & 15;
  const int cg = lane >> 4;
  const int rdoff = ((cg ^ ((q >> 1) & 3)) << 3);
  f32x4 acc[4][4] = {};
  for (int k0 = 0; k0 < K; k0 += 32) {
    __syncthreads();
    GLOAD16(gA0 + k0, lA0);
    GLOAD16(gA1 + k0, lA1);
    GLOAD16(gB0 + k0, lB0);
    GLOAD16(gB1 + k0, lB1);
    __syncthreads();
    bf16x8 af[4], bf[4];
    #pragma unroll
    for (int i = 0; i < 4; ++i)
      af[i] = *(const bf16x8*)&lA[(wr + i * 16 + q) * 32 + rdoff];
    #pragma unroll
    for (int j = 0; j < 4; ++j)
      bf[j] = *(const bf16x8*)&lB[(wc + j * 16 + q) * 32 + rdoff];
    #pragma unroll
    for (int i = 0; i < 4; ++i)
      #pragma unroll
      for (int j = 0; j < 4; ++j)
        acc[i][j] = __builtin_amdgcn_mfma_f32_16x16x32_bf16(af[i], bf[j], acc[i][j], 0, 0, 0);
  }
  const int rg4 = cg * 4;
  // xnew = resid + gemm; keep in acc; accumulate per-row partials (4 cols each)
  float ps[4][4], ps2[4][4];
  #pragma unroll
  for (int i = 0; i < 4; ++i)
    #pragma unroll
    for (int jj = 0; jj < 4; ++jj) { ps[i][jj] = 0.f; ps2[i][jj] = 0.f; }
  #pragma unroll
  for (int i = 0; i < 4; ++i) {
    #pragma unroll
    for (int j = 0; j < 4; ++j) {
      int col = wc + j * 16 + q;
      float bv = bias[col];
      #pragma unroll
      for (int jj = 0; jj < 4; ++jj) {
        int row = row0 + wr + i * 16 + rg4 + jj;
        float xv = xio[(size_t)row * 128 + col] + acc[i][j][jj] + bv;
        acc[i][j][jj] = xv;
        ps[i][jj] += xv;
        ps2[i][jj] += xv * xv;
      }
    }
  }
  // butterfly over the 16 q-lanes (same cg group) -> sums over this wave's 64 cols
  #pragma unroll
  for (int o = 1; o < 16; o <<= 1) {
    #pragma unroll
    for (int i = 0; i < 4; ++i)
      #pragma unroll
      for (int jj = 0; jj < 4; ++jj) {
        ps[i][jj]  += __shfl_xor(ps[i][jj], o);
        ps2[i][jj] += __shfl_xor(ps2[i][jj], o);
      }
  }
  if (q == 0) {
    #pragma unroll
    for (int i = 0; i < 4; ++i)
      #pragma unroll
      for (int jj = 0; jj < 4; ++jj) {
        int rl = wr + i * 16 + rg4 + jj;
        part[rl][whalf][0] = ps[i][jj];
        part[rl][whalf][1] = ps2[i][jj];
      }
  }
  __syncthreads();
  #pragma unroll
  for (int i = 0; i < 4; ++i) {
    #pragma unroll
    for (int jj = 0; jj < 4; ++jj) {
      int rl = wr + i * 16 + rg4 + jj;
      float S  = part[rl][0][0] + part[rl][1][0];
      float S2 = part[rl][0][1] + part[rl][1][1];
      float mean = S * (1.f / 128.f);
      float rstd = rsqrtf(S2 * (1.f / 128.f) - mean * mean + 1e-5f);
      int row = row0 + rl;
      #pragma unroll
      for (int j = 0; j < 4; ++j) {
        int col = wc + j * 16 + q;
        float xv = acc[i][j][jj];
        xio[(size_t)row * 128 + col] = xv;
        srcout[(size_t)row * 128 + col] = f2bf((xv - mean) * rstd * g[col] + be[col]);
      }
    }
  }
}

// ---------------------------------------------------------------- attention (32x32 MFMA flash)
// grid (NHEAD, BATCH), 256 threads = 4 waves. qkv: [T][384] bf16 (q pre-scaled by 0.25).
#define VSTR2 296   // Vt row stride (u16)
__global__ __launch_bounds__(256)
void k_attn(const u16* __restrict__ qkv, const int* __restrict__ mask,
            u16* __restrict__ out) {
  int h = blockIdx.x, b = blockIdx.y;
  __shared__ __align__(16) u16 Klin[9 * 512];     // frag-linear K: [tile][lane][8]
  __shared__ __align__(16) u16 Vt[16 * VSTR2];    // V transposed: [d][k]
  __shared__ int part[4];
  const int tid = threadIdx.x;
  int mv = (mask[b * SEQL + tid] != 0) ? 1 : 0;
  #pragma unroll
  for (int o = 32; o; o >>= 1) mv += __shfl_xor(mv, o);
  if ((tid & 63) == 0) part[tid >> 6] = mv;
  for (int idx = tid; idx < 576; idx += 256) {
    int r = idx >> 1, h2 = idx & 1;
    uint4 val = make_uint4(0, 0, 0, 0);
    if (r < NPOS)
      val = *(const uint4*)&qkv[((size_t)(b * NPOS + r)) * 384 + h * 16 + 128 + h2 * 8];
    *(uint4*)&Klin[(r >> 5) * 512 + h2 * 256 + (r & 31) * 8] = val;
  }
  for (int r = tid; r < 288; r += 256) {
    u16 tmp[16];
    if (r < NPOS) {
      const u16* vp = &qkv[((size_t)(b * NPOS + r)) * 384 + h * 16 + 256];
      *(uint4*)&tmp[0] = *(const uint4*)&vp[0];
      *(uint4*)&tmp[8] = *(const uint4*)&vp[8];
    } else {
      #pragma unroll
      for (int d = 0; d < 16; ++d) tmp[d] = 0;
    }
    #pragma unroll
    for (int d = 0; d < 16; ++d) Vt[d * VSTR2 + r] = tmp[d];
  }
  __syncthreads();
  const int nvalid = part[0] + part[1] + part[2] + part[3] + 3;
  const int ktiles = (nvalid + 31) >> 5;
  const int wave = tid >> 6, lane = tid & 63;
  const int q5 = lane & 31, hi = lane >> 5;
  const f32x16 zf = {};
  for (int qt = wave; qt < 9; qt += 4) {
    int qrow = qt * 32 + q5;
    int qr = (qrow < NPOS) ? qrow : (NPOS - 1);
    bf16x8 qf = *(const bf16x8*)&qkv[((size_t)(b * NPOS + qr)) * 384 + h * 16 + hi * 8];
    float m = -1e30f, l = 0.f;
    f32x16 acc = {};
    for (int kt = 0; kt < ktiles; ++kt) {
      bf16x8 kf = *(const bf16x8*)&Klin[kt * 512 + lane * 8];
      f32x16 s4 = __builtin_amdgcn_mfma_f32_32x32x16_bf16(kf, qf, zf, 0, 0, 0);
      float p[16];
      float tmax = -1e30f;
      #pragma unroll
      for (int r = 0; r < 16; ++r) {
        int kr = kt * 32 + (r & 3) + 8 * (r >> 2) + 4 * hi;
        float v = (kr < nvalid) ? s4[r] : -1e30f;
        p[r] = v;
        tmax = fmaxf(tmax, v);
      }
      tmax = fmaxf(tmax, __shfl_xor(tmax, 32));
      float mnew = fmaxf(m, tmax);
      float fac = __expf(m - mnew);
      float tsum = 0.f;
      #pragma unroll
      for (int r = 0; r < 16; ++r) { p[r] = __expf(p[r] - mnew); tsum += p[r]; }
      tsum += __shfl_xor(tsum, 32);
      l = l * fac + tsum;
      m = mnew;
      #pragma unroll
      for (int r = 0; r < 8; ++r) acc[r] *= fac;   // regs 8-15 stay 0
      u32 w[8], xw[8];
      #pragma unroll
      for (int i = 0; i < 8; ++i)
        asm("v_cvt_pk_bf16_f32 %0, %1, %2" : "=v"(w[i]) : "v"(p[2 * i]), "v"(p[2 * i + 1]));
      #pragma unroll
      for (int i = 0; i < 8; ++i) xw[i] = (u32)__shfl_xor((int)w[i], 32);
      union { u32 u[4]; bf16x8 v; } f1, f2;
      if (hi) {
        f1.u[0] = xw[2]; f1.u[1] = xw[3]; f1.u[2] = w[2]; f1.u[3] = w[3];
        f2.u[0] = xw[6]; f2.u[1] = xw[7]; f2.u[2] = w[6]; f2.u[3] = w[7];
      } else {
        f1.u[0] = w[0]; f1.u[1] = w[1]; f1.u[2] = xw[0]; f1.u[3] = xw[1];
        f2.u[0] = w[4]; f2.u[1] = w[5]; f2.u[2] = xw[4]; f2.u[3] = xw[5];
      }
      bf16x8 vf0 = {}, vf1 = {};
      if (q5 < 16) {
        vf0 = *(const bf16x8*)&Vt[q5 * VSTR2 + kt * 32 + hi * 8];
        vf1 = *(const bf16x8*)&Vt[q5 * VSTR2 + kt * 32 + 16 + hi * 8];
      }
      acc = __builtin_amdgcn_mfma_f32_32x32x16_bf16(vf0, f1.v, acc, 0, 0, 0);
      acc = __builtin_amdgcn_mfma_f32_32x32x16_bf16(vf1, f2.v, acc, 0, 0, 0);
    }
    if (qrow < NPOS) {
      float linv = 1.f / l;
      u16* op = &out[((size_t)(b * NPOS + qrow)) * HD + h * 16];
      u32 w0 = (u32)f2bf(acc[0] * linv) | ((u32)f2bf(acc[1] * linv) << 16);
      u32 w1 = (u32)f2bf(acc[2] * linv) | ((u32)f2bf(acc[3] * linv) << 16);
      u32 w2 = (u32)f2bf(acc[4] * linv) | ((u32)f2bf(acc[5] * linv) << 16);
      u32 w3 = (u32)f2bf(acc[6] * linv) | ((u32)f2bf(acc[7] * linv) << 16);
      *(uint2*)&op[4 * hi] = make_uint2(w0, w1);
      *(uint2*)&op[8 + 4 * hi] = make_uint2(w2, w3);
    }
  }
}

// ---------------------------------------------------------------- head
__global__ __launch_bounds__(128)
void k_head(const float* __restrict__ x, const float* __restrict__ bw,
            const float* __restrict__ bb, const float* __restrict__ cw,
             const float* __restrict__ cb, float* __restrict__ dout) {
  int b = blockIdx.x, n = threadIdx.x;
  __shared__ float lat[HD];
  __shared__ float redp[2], redss[2];
  float lv = x[((size_t)b * NPOS) * HD + n];
  lat[n] = lv;
  __syncthreads();
  float t = 0.f;
  for (int k = 0; k < HD; ++k) t += lat[k] * bw[k * HD + n];
  t += bb[n];
  t = fmaxf(t, 0.f);
  float p = t * cw[n];
  float ss = lv * lv;
  #pragma unroll
  for (int o = 32; o; o >>= 1) { p += __shfl_xor(p, o); ss += __shfl_xor(ss, o); }
  if ((n & 63) == 0) { redp[n >> 6] = p; redss[n >> 6] = ss; }
  __syncthreads();
  float psum = redp[0] + redp[1];
  float ssum = redss[0] + redss[1];
  if (n == 0) dout[b] = psum + cb[0];
  float nrm = fmaxf(sqrtf(ssum), 1e-12f);
  dout[256 + (size_t)b * HD + n] = lv / nrm;
}

// ---------------------------------------------------------------- launch
extern "C" void kernel_launch(void* const* d_in, const int* in_sizes, int n_in,
                              void* d_out, int out_size, void* d_ws, size_t ws_size,
                              hipStream_t stream) {
  const int* item_seq = (const int*)d_in[0];
  const int* action_seq = (const int*)d_in[1];
  const int* time_diff = (const int*)d_in[2];
  const int* mask = (const int*)d_in[3];
  const int* u_cv = (const int*)d_in[4];
  const int* u_cl = (const int*)d_in[5];
  const float* u_num = (const float*)d_in[6];
  const int* i_cv = (const int*)d_in[7];
  const int* i_cl = (const int*)d_in[8];
  const float* i_num = (const float*)d_in[9];
  const float* item_t = (const float*)d_in[10];
  const float* act_t = (const float*)d_in[11];
  const float* time_t = (const float*)d_in[12];
  const float* cat_t = (const float*)d_in[13];
  const float* num_W = (const float*)d_in[14];
  const float* gtok = (const float*)d_in[15];
  const float* ln1_g = (const float*)d_in[16];
  const float* ln1_b = (const float*)d_in[17];
  const float* qkv_w = (const float*)d_in[18];
  const float* qkv_b = (const float*)d_in[19];
  const float* out_w = (const float*)d_in[20];
  const float* out_b = (const float*)d_in[21];
  const float* w1 = (const float*)d_in[22];
  const float* b1 = (const float*)d_in[23];
  const float* w2 = (const float*)d_in[24];
  const float* b2 = (const float*)d_in[25];
  const float* ln2_g = (const float*)d_in[26];
  const float* ln2_b = (const float*)d_in[27];
  const float* bott_w = (const float*)d_in[28];
  const float* bott_b = (const float*)d_in[29];
  const float* cls_w = (const float*)d_in[30];
  const float* cls_b = (const float*)d_in[31];

  // workspace layout (bytes)
  const size_t off_x   = 0;                    // TTOK*128 f32  = 33,947,648
  const size_t off_src = 33947648;             // TTOK*128 bf16 = 16,973,824 (LN out / attn out)
  const size_t off_big = 50921472;             // TTOK*512 bf16 = 67,895,296 (qkv / h1)
  const size_t off_wT  = 118816768;            // 786,432 elems bf16
  const size_t need    = 120389632;
  if (ws_size < need) {
    fprintf(stderr, "kernel_launch: ws_size %zu < needed %zu\n", ws_size, need);
    return;
  }
  char* ws = (char*)d_ws;
  float* x   = (float*)(ws + off_x);
  u16* src   = (u16*)(ws + off_src);
  u16* big   = (u16*)(ws + off_big);
  u16* wT    = (u16*)(ws + off_wT);
  u16* qkvT  = wT;                 // [4][384][128]
  u16* outT  = wT + 196608;        // [4][128][128]
  u16* w1T   = wT + 262144;        // [4][512][128]
  u16* w2T   = wT + 524288;        // [4][128][512]

  k_transpose<<<(4 * 128 * 384 + 255) / 256, 256, 0, stream>>>(qkv_w, qkvT, 4, 128, 384);
  k_transpose<<<(4 * 128 * 128 + 255) / 256, 256, 0, stream>>>(out_w, outT, 4, 128, 128);
  k_transpose<<<(4 * 128 * 512 + 255) / 256, 256, 0, stream>>>(w1, w1T, 4, 128, 512);
  k_transpose<<<(4 * 512 * 128 + 255) / 256, 256, 0, stream>>>(w2, w2T, 4, 512, 128);

  k_build<<<dim3(NPOS, BATCH), 128, 0, stream>>>(
      item_seq, action_seq, time_diff, u_cv, u_cl, u_num, i_cv, i_cl, i_num,
      item_t, act_t, time_t, cat_t, num_W, gtok, x);

  // layer-0 LN1 (subsequent LN1s are fused into the previous layer's MLP2)
  k_ln<<<TTOK / 4, 256, 0, stream>>>(x, ln1_g, ln1_b, src);

  const int rt = TTOK / 128;  // 518
  for (int dd = 0; dd < DEPTH; ++dd) {
    // QKV (q cols pre-scaled by 0.25): src -> big
    k_gemm<0, true><<<dim3(rt, 3), 256, 0, stream>>>(
        src, qkvT + dd * 49152, qkv_b + dd * 384, big, 128, 384);
    // attention: big -> src
    k_attn<<<dim3(NHEAD, BATCH), 256, 0, stream>>>(big, mask, src);
    // proj + residual + fused LN2: src(attn) -> x, src(LN2 out)
    k_gemm_ln<<<dim3(rt, 1), 256, 0, stream>>>(
        src, outT + dd * 16384, out_b + dd * HD, x,
        ln2_g + dd * HD, ln2_b + dd * HD, src, 128);
    // MLP1 (gelu): src -> big
    k_gemm<1, false><<<dim3(rt, 4), 256, 0, stream>>>(
        src, w1T + dd * 65536, b1 + dd * FF, big, 128, 512);
    // MLP2 + residual + fused LN1 of next layer: big -> x, src
    const float* ng = (dd < 3) ? (ln1_g + (dd + 1) * HD) : (ln1_g + dd * HD);
    const float* nb = (dd < 3) ? (ln1_b + (dd + 1) * HD) : (ln1_b + dd * HD);
    k_gemm_ln<<<dim3(rt, 1), 256, 0, stream>>>(
        big, w2T + dd * 65536, b2 + dd * HD, x, ng, nb, src, 512);
  }

  k_head<<<BATCH, 128, 0, stream>>>(x, bott_w, bott_b, cls_w, cls_b, (float*)d_out);
}

// Round 9
// 806.799 us; speedup vs baseline: 1.5880x; 1.0422x over previous
//
#include <hip/hip_runtime.h>
#include <cstdio>

// Problem constants
#define BATCH 256
#define SEQL 256
#define NPOS 259            // 3 + SEQL
#define TTOK (BATCH*NPOS)   // 66304 = 518 * 128
#define HD 128
#define NHEAD 8
#define FF 512
#define DEPTH 4
#define CVOC 50001

typedef unsigned short u16;
typedef unsigned int u32;
typedef __bf16 bf16x8 __attribute__((ext_vector_type(8)));
typedef float f32x4 __attribute__((ext_vector_type(4)));
typedef float f32x16 __attribute__((ext_vector_type(16)));

typedef const __attribute__((address_space(1))) u32 gas_u32;
typedef __attribute__((address_space(3))) u32 las_u32;
#define GLOAD16(gptr, lptr) \
  __builtin_amdgcn_global_load_lds((gas_u32*)(gptr), (las_u32*)(lptr), 16, 0, 0)

// SCALE * log2(e): q pre-scaled so attention softmax can use native exp2
#define QSCALE 0.36067376022224085f

__device__ __forceinline__ u16 f2bf(float f) {
  u32 i = __float_as_uint(f);
  u32 r = (i + 0x7FFFu + ((i >> 16) & 1u)) >> 16;   // RNE
  return (u16)r;
}

// ---------------------------------------------------------------- merged transpose + downcast
// wT layout: [qkvT 196608][outT 65536][w1T 262144][w2T 262144] (u16 elems)
__global__ void k_transpose_all(const float* __restrict__ qkv_w, const float* __restrict__ out_w,
                                const float* __restrict__ w1, const float* __restrict__ w2,
                                u16* __restrict__ wT) {
  int idx = blockIdx.x * 256 + threadIdx.x;
  const float* in; int K, N, local;
  if (idx < 196608)      { in = qkv_w; K = 128; N = 384; local = idx; }
  else if (idx < 262144) { in = out_w; K = 128; N = 128; local = idx - 196608; }
  else if (idx < 524288) { in = w1;    K = 128; N = 512; local = idx - 262144; }
  else if (idx < 786432) { in = w2;    K = 512; N = 128; local = idx - 524288; }
  else return;
  int k = local % K; int rem = local / K; int n = rem % N; int d = rem / N;
  wT[idx] = f2bf(in[(d * K + k) * N + n]);
}

// ---------------------------------------------------------------- build x (+ fused layer-0 LN1)
// grid (NPOS, BATCH), 128 threads = one token row. Writes x fp32 and src = LN1_0(x) bf16.
__global__ __launch_bounds__(128)
void k_build(const int* __restrict__ item_seq, const int* __restrict__ act_seq,
             const int* __restrict__ tdiff,
             const int* __restrict__ ucv, const int* __restrict__ ucl, const float* __restrict__ unum,
             const int* __restrict__ icv, const int* __restrict__ icl, const float* __restrict__ inum,
             const float* __restrict__ item_t, const float* __restrict__ act_t,
             const float* __restrict__ time_t, const float* __restrict__ cat_t,
             const float* __restrict__ numW, const float* __restrict__ gtok,
             const float* __restrict__ g, const float* __restrict__ be,
             float* __restrict__ x, u16* __restrict__ src) {
  int pos = blockIdx.x, b = blockIdx.y, h = threadIdx.x;
  float v;
  if (pos == 0) {
    v = gtok[h];
  } else if (pos <= 2) {
    const int* cv = (pos == 1) ? ucv : icv;
    const int* cl = (pos == 1) ? ucl : icl;
    const float* nm = (pos == 1) ? unum : inum;
    float acc = 0.f;
    for (int f = 0; f < 8; ++f) {
      float s = 0.f;
      for (int k = 0; k < 8; ++k) {
        int idx = cv[(b * 8 + f) * 8 + k];
        s += cat_t[((size_t)f * CVOC + idx) * HD + h];
      }
      acc += s / (float)cl[b * 8 + f];
    }
    for (int f = 0; f < 4; ++f)
      for (int d = 0; d < 32; ++d)
        acc += nm[(b * 4 + f) * 32 + d] * numW[(f * 32 + d) * HD + h];
    v = acc * (1.f / 12.f);
  } else {
    int l = pos - 3;
    v = item_t[(size_t)item_seq[b * SEQL + l] * HD + h]
      + act_t[(size_t)act_seq[b * SEQL + l] * HD + h]
      + time_t[(size_t)tdiff[b * SEQL + l] * HD + h];
  }
  size_t t = (size_t)b * NPOS + pos;
  x[t * HD + h] = v;
  // fused LN over the 128-elem row (2 waves)
  __shared__ float red[2][2];
  float s = v, s2 = v * v;
  #pragma unroll
  for (int o = 32; o; o >>= 1) { s += __shfl_xor(s, o); s2 += __shfl_xor(s2, o); }
  if ((h & 63) == 0) { red[h >> 6][0] = s; red[h >> 6][1] = s2; }
  __syncthreads();
  float S = red[0][0] + red[1][0], S2 = red[0][1] + red[1][1];
  float mean = S * (1.f / HD);
  float rstd = rsqrtf(S2 * (1.f / HD) - mean * mean + 1e-5f);
  src[t * HD + h] = f2bf((v - mean) * rstd * g[h] + be[h]);
}

// ---------------------------------------------------------------- GEMM (MFMA, m97 structure, BK=32)
// Y[T x N] = act(X @ W + bias); WT[N][K] bf16. Tile 128x128, 4 waves 2x2.
// ACT 1 = exact gelu. QS: cols<128 scaled by QSCALE (attn SCALE*log2e folded into q).
template <int ACT, bool QS>
__global__ __launch_bounds__(256)
void k_gemm(const u16* __restrict__ X, const u16* __restrict__ WT,
            const float* __restrict__ bias, u16* __restrict__ outp,
            int K, int N) {
  __shared__ __align__(16) u16 lA[128 * 32];
  __shared__ __align__(16) u16 lB[128 * 32];
  const int tid = threadIdx.x;
  const int wave = tid >> 6, lane = tid & 63;
  const int row0 = blockIdx.x * 128;
  const int n0 = blockIdx.y * 128;
  const int wr = (wave >> 1) * 64, wc = (wave & 1) * 64;
  const int sr = lane >> 2;
  const int sc = ((lane & 3) ^ ((lane >> 3) & 3)) << 3;
  const u16* gA0 = X  + (size_t)(row0 + wave * 16 + sr) * K + sc;
  const u16* gA1 = X  + (size_t)(row0 + 64 + wave * 16 + sr) * K + sc;
  const u16* gB0 = WT + (size_t)(n0 + wave * 16 + sr) * K + sc;
  const u16* gB1 = WT + (size_t)(n0 + 64 + wave * 16 + sr) * K + sc;
  u16* lA0 = &lA[wave * 512];
  u16* lA1 = &lA[2048 + wave * 512];
  u16* lB0 = &lB[wave * 512];
  u16* lB1 = &lB[2048 + wave * 512];
  const int q = lane & 15;
  const int cg = lane >> 4;
  const int rdoff = ((cg ^ ((q >> 1) & 3)) << 3);
  f32x4 acc[4][4] = {};
  for (int k0 = 0; k0 < K; k0 += 32) {
    __syncthreads();
    GLOAD16(gA0 + k0, lA0);
    GLOAD16(gA1 + k0, lA1);
    GLOAD16(gB0 + k0, lB0);
    GLOAD16(gB1 + k0, lB1);
    __syncthreads();
    bf16x8 af[4], bf[4];
    #pragma unroll
    for (int i = 0; i < 4; ++i)
      af[i] = *(const bf16x8*)&lA[(wr + i * 16 + q) * 32 + rdoff];
    #pragma unroll
    for (int j = 0; j < 4; ++j)
      bf[j] = *(const bf16x8*)&lB[(wc + j * 16 + q) * 32 + rdoff];
    #pragma unroll
    for (int i = 0; i < 4; ++i)
      #pragma unroll
      for (int j = 0; j < 4; ++j)
        acc[i][j] = __builtin_amdgcn_mfma_f32_16x16x32_bf16(af[i], bf[j], acc[i][j], 0, 0, 0);
  }
  const int rg4 = cg * 4;
  #pragma unroll
  for (int i = 0; i < 4; ++i) {
    #pragma unroll
    for (int j = 0; j < 4; ++j) {
      int col = n0 + wc + j * 16 + q;
      float bv = bias[col];
      float scl = (QS && col < 128) ? QSCALE : 1.f;
      #pragma unroll
      for (int jj = 0; jj < 4; ++jj) {
        int row = row0 + wr + i * 16 + rg4 + jj;
        float v = acc[i][j][jj] + bv;
        if (ACT == 1) v = 0.5f * v * (1.f + erff(v * 0.70710678118654752f));
        if (QS) v *= scl;
        outp[(size_t)row * N + col] = f2bf(v);
      }
    }
  }
}

// ---------------------------------------------------------------- residual GEMM + fused LN (N=128)
__global__ __launch_bounds__(256)
void k_gemm_ln(const u16* __restrict__ X, const u16* __restrict__ WT,
               const float* __restrict__ bias, float* __restrict__ xio,
               const float* __restrict__ g, const float* __restrict__ be,
               u16* __restrict__ srcout, int K) {
  __shared__ __align__(16) u16 lA[128 * 32];
  __shared__ __align__(16) u16 lB[128 * 32];
  __shared__ float part[128][2][2];
  const int tid = threadIdx.x;
  const int wave = tid >> 6, lane = tid & 63;
  const int row0 = blockIdx.x * 128;
  const int wr = (wave >> 1) * 64, wc = (wave & 1) * 64;
  const int whalf = wave & 1;
  const int sr = lane >> 2;
  const int sc = ((lane & 3) ^ ((lane >> 3) & 3)) << 3;
  const u16* gA0 = X  + (size_t)(row0 + wave * 16 + sr) * K + sc;
  const u16* gA1 = X  + (size_t)(row0 + 64 + wave * 16 + sr) * K + sc;
  const u16* gB0 = WT + (size_t)(wave * 16 + sr) * K + sc;
  const u16* gB1 = WT + (size_t)(64 + wave * 16 + sr) * K + sc;
  u16* lA0 = &lA[wave * 512];
  u16* lA1 = &lA[2048 + wave * 512];
  u16* lB0 = &lB[wave * 512];
  u16* lB1 = &lB[2048 + wave * 512];
  const int q = lane & 15;
  const int cg = lane >> 4;
  const int rdoff = ((cg ^ ((q >> 1) & 3)) << 3);
  f32x4 acc[4][4] = {};
  for (int k0 = 0; k0 < K; k0 += 32) {
    __syncthreads();
    GLOAD16(gA0 + k0, lA0);
    GLOAD16(gA1 + k0, lA1);
    GLOAD16(gB0 + k0, lB0);
    GLOAD16(gB1 + k0, lB1);
    __syncthreads();
    bf16x8 af[4], bf[4];
    #pragma unroll
    for (int i = 0; i < 4; ++i)
      af[i] = *(const bf16x8*)&lA[(wr + i * 16 + q) * 32 + rdoff];
    #pragma unroll
    for (int j = 0; j < 4; ++j)
      bf[j] = *(const bf16x8*)&lB[(wc + j * 16 + q) * 32 + rdoff];
    #pragma unroll
    for (int i = 0; i < 4; ++i)
      #pragma unroll
      for (int j = 0; j < 4; ++j)
        acc[i][j] = __builtin_amdgcn_mfma_f32_16x16x32_bf16(af[i], bf[j], acc[i][j], 0, 0, 0);
  }
  const int rg4 = cg * 4;
  float ps[4][4], ps2[4][4];
  #pragma unroll
  for (int i = 0; i < 4; ++i)
    #pragma unroll
    for (int jj = 0; jj < 4; ++jj) { ps[i][jj] = 0.f; ps2[i][jj] = 0.f; }
  #pragma unroll
  for (int i = 0; i < 4; ++i) {
    #pragma unroll
    for (int j = 0; j < 4; ++j) {
      int col = wc + j * 16 + q;
      float bv = bias[col];
      #pragma unroll
      for (int jj = 0; jj < 4; ++jj) {
        int row = row0 + wr + i * 16 + rg4 + jj;
        float xv = xio[(size_t)row * 128 + col] + acc[i][j][jj] + bv;
        acc[i][j][jj] = xv;
        ps[i][jj] += xv;
        ps2[i][jj] += xv * xv;
      }
    }
  }
  #pragma unroll
  for (int o = 1; o < 16; o <<= 1) {
    #pragma unroll
    for (int i = 0; i < 4; ++i)
      #pragma unroll
      for (int jj = 0; jj < 4; ++jj) {
        ps[i][jj]  += __shfl_xor(ps[i][jj], o);
        ps2[i][jj] += __shfl_xor(ps2[i][jj], o);
      }
  }
  if (q == 0) {
    #pragma unroll
    for (int i = 0; i < 4; ++i)
      #pragma unroll
      for (int jj = 0; jj < 4; ++jj) {
        int rl = wr + i * 16 + rg4 + jj;
        part[rl][whalf][0] = ps[i][jj];
        part[rl][whalf][1] = ps2[i][jj];
      }
  }
  __syncthreads();
  #pragma unroll
  for (int i = 0; i < 4; ++i) {
    #pragma unroll
    for (int jj = 0; jj < 4; ++jj) {
      int rl = wr + i * 16 + rg4 + jj;
      float S  = part[rl][0][0] + part[rl][1][0];
      float S2 = part[rl][0][1] + part[rl][1][1];
      float mean = S * (1.f / 128.f);
      float rstd = rsqrtf(S2 * (1.f / 128.f) - mean * mean + 1e-5f);
      int row = row0 + rl;
      #pragma unroll
      for (int j = 0; j < 4; ++j) {
        int col = wc + j * 16 + q;
        float xv = acc[i][j][jj];
        xio[(size_t)row * 128 + col] = xv;
        srcout[(size_t)row * 128 + col] = f2bf((xv - mean) * rstd * g[col] + be[col]);
      }
    }
  }
}

// ---------------------------------------------------------------- attention (32x32 MFMA flash)
// grid (NHEAD, BATCH), 576 threads = 9 waves, ONE q-tile per wave (no tail imbalance).
// qkv: [T][384] bf16, q pre-scaled by SCALE*log2e -> softmax uses native exp2.
#define VSTR2 296   // Vt row stride (u16)
__global__ __launch_bounds__(576)
void k_attn(const u16* __restrict__ qkv, const int* __restrict__ mask,
            u16* __restrict__ out) {
  int h = blockIdx.x, b = blockIdx.y;
  __shared__ __align__(16) u16 Klin[9 * 512];     // frag-linear K: [tile][lane][8]
  __shared__ __align__(16) u16 Vt[16 * VSTR2];    // V transposed: [d][k]
  __shared__ int part[4];
  const int tid = threadIdx.x;
  if (tid < 256) {
    int mv = (mask[b * SEQL + tid] != 0) ? 1 : 0;
    #pragma unroll
    for (int o = 32; o; o >>= 1) mv += __shfl_xor(mv, o);
    if ((tid & 63) == 0) part[tid >> 6] = mv;
  }
  // K staging: element K[r][d] -> Klin[(r>>5)*512 + (d>>3)*256 + (r&31)*8 + (d&7)]
  {
    int r = tid >> 1, h2 = tid & 1;
    uint4 val = make_uint4(0, 0, 0, 0);
    if (r < NPOS)
      val = *(const uint4*)&qkv[((size_t)(b * NPOS + r)) * 384 + h * 16 + 128 + h2 * 8];
    *(uint4*)&Klin[(r >> 5) * 512 + h2 * 256 + (r & 31) * 8] = val;
  }
  // V staging: Vt[d][r] = V[r][d]
  if (tid < 288) {
    int r = tid;
    u16 tmp[16];
    if (r < NPOS) {
      const u16* vp = &qkv[((size_t)(b * NPOS + r)) * 384 + h * 16 + 256];
      *(uint4*)&tmp[0] = *(const uint4*)&vp[0];
      *(uint4*)&tmp[8] = *(const uint4*)&vp[8];
    } else {
      #pragma unroll
      for (int d = 0; d < 16; ++d) tmp[d] = 0;
    }
    #pragma unroll
    for (int d = 0; d < 16; ++d) Vt[d * VSTR2 + r] = tmp[d];
  }
  __syncthreads();
  const int nvalid = part[0] + part[1] + part[2] + part[3] + 3;
  const int ktiles = (nvalid + 31) >> 5;
  const int wave = tid >> 6, lane = tid & 63;
  const int q5 = lane & 31, hi = lane >> 5;
  const f32x16 zf = {};
  const int qt = wave;                 // one q-tile per wave, qt in [0,9)
  int qrow = qt * 32 + q5;
  int qr = (qrow < NPOS) ? qrow : (NPOS - 1);
  bf16x8 qf = *(const bf16x8*)&qkv[((size_t)(b * NPOS + qr)) * 384 + h * 16 + hi * 8];
  float m = -1e30f, l = 0.f;
  f32x16 acc = {};
  for (int kt = 0; kt < ktiles; ++kt) {
    bf16x8 kf = *(const bf16x8*)&Klin[kt * 512 + lane * 8];
    __builtin_amdgcn_s_setprio(1);
    f32x16 s4 = __builtin_amdgcn_mfma_f32_32x32x16_bf16(kf, qf, zf, 0, 0, 0);
    __builtin_amdgcn_s_setprio(0);
    float p[16];
    float tmax = -1e30f;
    #pragma unroll
    for (int r = 0; r < 16; ++r) {
      int kr = kt * 32 + (r & 3) + 8 * (r >> 2) + 4 * hi;
      float v = (kr < nvalid) ? s4[r] : -1e30f;
      p[r] = v;
      tmax = fmaxf(tmax, v);
    }
    tmax = fmaxf(tmax, __shfl_xor(tmax, 32));
    float mnew = fmaxf(m, tmax);
    float fac = exp2f(m - mnew);
    float tsum = 0.f;
    #pragma unroll
    for (int r = 0; r < 16; ++r) { p[r] = exp2f(p[r] - mnew); tsum += p[r]; }
    tsum += __shfl_xor(tsum, 32);
    l = l * fac + tsum;
    m = mnew;
    #pragma unroll
    for (int r = 0; r < 8; ++r) acc[r] *= fac;   // regs 8-15 stay 0
    u32 w[8], xw[8];
    #pragma unroll
    for (int i = 0; i < 8; ++i)
      asm("v_cvt_pk_bf16_f32 %0, %1, %2" : "=v"(w[i]) : "v"(p[2 * i]), "v"(p[2 * i + 1]));
    #pragma unroll
    for (int i = 0; i < 8; ++i) xw[i] = (u32)__shfl_xor((int)w[i], 32);
    union { u32 u[4]; bf16x8 v; } f1, f2;
    if (hi) {
      f1.u[0] = xw[2]; f1.u[1] = xw[3]; f1.u[2] = w[2]; f1.u[3] = w[3];
      f2.u[0] = xw[6]; f2.u[1] = xw[7]; f2.u[2] = w[6]; f2.u[3] = w[7];
    } else {
      f1.u[0] = w[0]; f1.u[1] = w[1]; f1.u[2] = xw[0]; f1.u[3] = xw[1];
      f2.u[0] = w[4]; f2.u[1] = w[5]; f2.u[2] = xw[4]; f2.u[3] = xw[5];
    }
    bf16x8 vf0 = {}, vf1 = {};
    if (q5 < 16) {
      vf0 = *(const bf16x8*)&Vt[q5 * VSTR2 + kt * 32 + hi * 8];
      vf1 = *(const bf16x8*)&Vt[q5 * VSTR2 + kt * 32 + 16 + hi * 8];
    }
    __builtin_amdgcn_s_setprio(1);
    acc = __builtin_amdgcn_mfma_f32_32x32x16_bf16(vf0, f1.v, acc, 0, 0, 0);
    acc = __builtin_amdgcn_mfma_f32_32x32x16_bf16(vf1, f2.v, acc, 0, 0, 0);
    __builtin_amdgcn_s_setprio(0);
  }
  if (qrow < NPOS) {
    float linv = 1.f / l;
    u16* op = &out[((size_t)(b * NPOS + qrow)) * HD + h * 16];
    u32 w0 = (u32)f2bf(acc[0] * linv) | ((u32)f2bf(acc[1] * linv) << 16);
    u32 w1 = (u32)f2bf(acc[2] * linv) | ((u32)f2bf(acc[3] * linv) << 16);
    u32 w2 = (u32)f2bf(acc[4] * linv) | ((u32)f2bf(acc[5] * linv) << 16);
    u32 w3 = (u32)f2bf(acc[6] * linv) | ((u32)f2bf(acc[7] * linv) << 16);
    *(uint2*)&op[4 * hi] = make_uint2(w0, w1);
    *(uint2*)&op[8 + 4 * hi] = make_uint2(w2, w3);
  }
}

// ---------------------------------------------------------------- head
__global__ __launch_bounds__(128)
void k_head(const float* __restrict__ x, const float* __restrict__ bw,
            const float* __restrict__ bb, const float* __restrict__ cw,
            const float* __restrict__ cb, float* __restrict__ dout) {
  int b = blockIdx.x, n = threadIdx.x;
  __shared__ float lat[HD];
  __shared__ float redp[2], redss[2];
  float lv = x[((size_t)b * NPOS) * HD + n];
  lat[n] = lv;
  __syncthreads();
  float t = 0.f;
  for (int k = 0; k < HD; ++k) t += lat[k] * bw[k * HD + n];
  t += bb[n];
  t = fmaxf(t, 0.f);
  float p = t * cw[n];
  float ss = lv * lv;
  #pragma unroll
  for (int o = 32; o; o >>= 1) { p += __shfl_xor(p, o); ss += __shfl_xor(ss, o); }
  if ((n & 63) == 0) { redp[n >> 6] = p; redss[n >> 6] = ss; }
  __syncthreads();
  float psum = redp[0] + redp[1];
  float ssum = redss[0] + redss[1];
  if (n == 0) dout[b] = psum + cb[0];
  float nrm = fmaxf(sqrtf(ssum), 1e-12f);
  dout[256 + (size_t)b * HD + n] = lv / nrm;
}

// ---------------------------------------------------------------- launch
extern "C" void kernel_launch(void* const* d_in, const int* in_sizes, int n_in,
                              void* d_out, int out_size, void* d_ws, size_t ws_size,
                              hipStream_t stream) {
  const int* item_seq = (const int*)d_in[0];
  const int* action_seq = (const int*)d_in[1];
  const int* time_diff = (const int*)d_in[2];
  const int* mask = (const int*)d_in[3];
  const int* u_cv = (const int*)d_in[4];
  const int* u_cl = (const int*)d_in[5];
  const float* u_num = (const float*)d_in[6];
  const int* i_cv = (const int*)d_in[7];
  const int* i_cl = (const int*)d_in[8];
  const float* i_num = (const float*)d_in[9];
  const float* item_t = (const float*)d_in[10];
  const float* act_t = (const float*)d_in[11];
  const float* time_t = (const float*)d_in[12];
  const float* cat_t = (const float*)d_in[13];
  const float* num_W = (const float*)d_in[14];
  const float* gtok = (const float*)d_in[15];
  const float* ln1_g = (const float*)d_in[16];
  const float* ln1_b = (const float*)d_in[17];
  const float* qkv_w = (const float*)d_in[18];
  const float* qkv_b = (const float*)d_in[19];
  const float* out_w = (const float*)d_in[20];
  const float* out_b = (const float*)d_in[21];
  const float* w1 = (const float*)d_in[22];
  const float* b1 = (const float*)d_in[23];
  const float* w2 = (const float*)d_in[24];
  const float* b2 = (const float*)d_in[25];
  const float* ln2_g = (const float*)d_in[26];
  const float* ln2_b = (const float*)d_in[27];
  const float* bott_w = (const float*)d_in[28];
  const float* bott_b = (const float*)d_in[29];
  const float* cls_w = (const float*)d_in[30];
  const float* cls_b = (const float*)d_in[31];

  // workspace layout (bytes)
  const size_t off_x   = 0;                    // TTOK*128 f32  = 33,947,648
  const size_t off_src = 33947648;             // TTOK*128 bf16 = 16,973,824 (LN out / attn out)
  const size_t off_big = 50921472;             // TTOK*512 bf16 = 67,895,296 (qkv / h1)
  const size_t off_wT  = 118816768;            // 786,432 elems bf16
  const size_t need    = 120389632;
  if (ws_size < need) {
    fprintf(stderr, "kernel_launch: ws_size %zu < needed %zu\n", ws_size, need);
    return;
  }
  char* ws = (char*)d_ws;
  float* x   = (float*)(ws + off_x);
  u16* src   = (u16*)(ws + off_src);
  u16* big   = (u16*)(ws + off_big);
  u16* wT    = (u16*)(ws + off_wT);
  u16* qkvT  = wT;                 // [4][384][128]
  u16* outT  = wT + 196608;        // [4][128][128]
  u16* w1T   = wT + 262144;        // [4][512][128]
  u16* w2T   = wT + 524288;        // [4][128][512]

  k_transpose_all<<<3072, 256, 0, stream>>>(qkv_w, out_w, w1, w2, wT);

  // build + fused layer-0 LN1 (subsequent LN1s fused into previous layer's MLP2)
  k_build<<<dim3(NPOS, BATCH), 128, 0, stream>>>(
      item_seq, action_seq, time_diff, u_cv, u_cl, u_num, i_cv, i_cl, i_num,
      item_t, act_t, time_t, cat_t, num_W, gtok, ln1_g, ln1_b, x, src);

  const int rt = TTOK / 128;  // 518
  for (int dd = 0; dd < DEPTH; ++dd) {
    // QKV (q cols pre-scaled by QSCALE): src -> big
    k_gemm<0, true><<<dim3(rt, 3), 256, 0, stream>>>(
        src, qkvT + dd * 49152, qkv_b + dd * 384, big, 128, 384);
    // attention: big -> src
    k_attn<<<dim3(NHEAD, BATCH), 576, 0, stream>>>(big, mask, src);
    // proj + residual + fused LN2: src(attn) -> x, src(LN2 out)
    k_gemm_ln<<<dim3(rt, 1), 256, 0, stream>>>(
        src, outT + dd * 16384, out_b + dd * HD, x,
        ln2_g + dd * HD, ln2_b + dd * HD, src, 128);
    // MLP1 (gelu): src -> big
    k_gemm<1, false><<<dim3(rt, 4), 256, 0, stream>>>(
        src, w1T + dd * 65536, b1 + dd * FF, big, 128, 512);
    // MLP2 + residual + fused LN1 of next layer: big -> x, src
    const float* ng = (dd < 3) ? (ln1_g + (dd + 1) * HD) : (ln1_g + dd * HD);
    const float* nb = (dd < 3) ? (ln1_b + (dd + 1) * HD) : (ln1_b + dd * HD);
    k_gemm_ln<<<dim3(rt, 1), 256, 0, stream>>>(
        big, w2T + dd * 65536, b2 + dd * HD, x, ng, nb, src, 512);
  }

  k_head<<<BATCH, 128, 0, stream>>>(x, bott_w, bott_b, cls_w, cls_b, (float*)d_out);
}

// Round 10
// 784.803 us; speedup vs baseline: 1.6325x; 1.0280x over previous
//
#include <hip/hip_runtime.h>
#include <cstdio>

// Problem constants
#define BATCH 256
#define SEQL 256
#define NPOS 259            // 3 + SEQL
#define TTOK (BATCH*NPOS)   // 66304 = 518 * 128
#define HD 128
#define NHEAD 8
#define FF 512
#define DEPTH 4
#define CVOC 50001

typedef unsigned short u16;
typedef unsigned int u32;
typedef __bf16 bf16x8 __attribute__((ext_vector_type(8)));
typedef float f32x4 __attribute__((ext_vector_type(4)));
typedef float f32x16 __attribute__((ext_vector_type(16)));

typedef const __attribute__((address_space(1))) u32 gas_u32;
typedef __attribute__((address_space(3))) u32 las_u32;
#define GLOAD16(gptr, lptr) \
  __builtin_amdgcn_global_load_lds((gas_u32*)(gptr), (las_u32*)(lptr), 16, 0, 0)

// SCALE * log2(e): q pre-scaled so attention softmax can use native exp2
#define QSCALE 0.36067376022224085f

__device__ __forceinline__ u16 f2bf(float f) {
  u32 i = __float_as_uint(f);
  u32 r = (i + 0x7FFFu + ((i >> 16) & 1u)) >> 16;   // RNE
  return (u16)r;
}

// ---------------------------------------------------------------- merged transpose + downcast
// wT layout: [qkvT 196608][outT 65536][w1T 262144][w2T 262144] (u16 elems)
__global__ void k_transpose_all(const float* __restrict__ qkv_w, const float* __restrict__ out_w,
                                const float* __restrict__ w1, const float* __restrict__ w2,
                                u16* __restrict__ wT) {
  int idx = blockIdx.x * 256 + threadIdx.x;
  const float* in; int K, N, local;
  if (idx < 196608)      { in = qkv_w; K = 128; N = 384; local = idx; }
  else if (idx < 262144) { in = out_w; K = 128; N = 128; local = idx - 196608; }
  else if (idx < 524288) { in = w1;    K = 128; N = 512; local = idx - 262144; }
  else if (idx < 786432) { in = w2;    K = 512; N = 128; local = idx - 524288; }
  else return;
  int k = local % K; int rem = local / K; int n = rem % N; int d = rem / N;
  wT[idx] = f2bf(in[(d * K + k) * N + n]);
}

// ---------------------------------------------------------------- build x (+ fused layer-0 LN1)
__global__ __launch_bounds__(128)
void k_build(const int* __restrict__ item_seq, const int* __restrict__ act_seq,
             const int* __restrict__ tdiff,
             const int* __restrict__ ucv, const int* __restrict__ ucl, const float* __restrict__ unum,
             const int* __restrict__ icv, const int* __restrict__ icl, const float* __restrict__ inum,
             const float* __restrict__ item_t, const float* __restrict__ act_t,
             const float* __restrict__ time_t, const float* __restrict__ cat_t,
             const float* __restrict__ numW, const float* __restrict__ gtok,
             const float* __restrict__ g, const float* __restrict__ be,
             float* __restrict__ x, u16* __restrict__ src) {
  int pos = blockIdx.x, b = blockIdx.y, h = threadIdx.x;
  float v;
  if (pos == 0) {
    v = gtok[h];
  } else if (pos <= 2) {
    const int* cv = (pos == 1) ? ucv : icv;
    const int* cl = (pos == 1) ? ucl : icl;
    const float* nm = (pos == 1) ? unum : inum;
    float acc = 0.f;
    for (int f = 0; f < 8; ++f) {
      float s = 0.f;
      for (int k = 0; k < 8; ++k) {
        int idx = cv[(b * 8 + f) * 8 + k];
        s += cat_t[((size_t)f * CVOC + idx) * HD + h];
      }
      acc += s / (float)cl[b * 8 + f];
    }
    for (int f = 0; f < 4; ++f)
      for (int d = 0; d < 32; ++d)
        acc += nm[(b * 4 + f) * 32 + d] * numW[(f * 32 + d) * HD + h];
    v = acc * (1.f / 12.f);
  } else {
    int l = pos - 3;
    v = item_t[(size_t)item_seq[b * SEQL + l] * HD + h]
      + act_t[(size_t)act_seq[b * SEQL + l] * HD + h]
      + time_t[(size_t)tdiff[b * SEQL + l] * HD + h];
  }
  size_t t = (size_t)b * NPOS + pos;
  x[t * HD + h] = v;
  __shared__ float red[2][2];
  float s = v, s2 = v * v;
  #pragma unroll
  for (int o = 32; o; o >>= 1) { s += __shfl_xor(s, o); s2 += __shfl_xor(s2, o); }
  if ((h & 63) == 0) { red[h >> 6][0] = s; red[h >> 6][1] = s2; }
  __syncthreads();
  float S = red[0][0] + red[1][0], S2 = red[0][1] + red[1][1];
  float mean = S * (1.f / HD);
  float rstd = rsqrtf(S2 * (1.f / HD) - mean * mean + 1e-5f);
  src[t * HD + h] = f2bf((v - mean) * rstd * g[h] + be[h]);
}

// ---------------------------------------------------------------- GEMM, A-resident multi-N
// Y[128-row stripe x NCH*128] = act(X @ W + bias); WT[N][128] bf16, K=128 fixed.
// A (128x128) staged once in LDS (32KB, swizzled); per n-chunk, B staged 8KB/k-step.
// Grid: TTOK/128 blocks, 256 thr. K-order per output identical to the R5 kernel.
template <int NCH, int ACT, bool QS>
__global__ __launch_bounds__(256)
void k_gemm_nres(const u16* __restrict__ X, const u16* __restrict__ WT,
                 const float* __restrict__ bias, u16* __restrict__ outp) {
  const int K = 128, N = NCH * 128;
  __shared__ __align__(16) u16 lA[4][128 * 32];   // [kt][row-group*512 + lane*8]
  __shared__ __align__(16) u16 lB[128 * 32];
  const int tid = threadIdx.x;
  const int wave = tid >> 6, lane = tid & 63;
  const int row0 = blockIdx.x * 128;
  const int wr = (wave >> 1) * 64, wc = (wave & 1) * 64;
  const int sr = lane >> 2;
  const int sc = ((lane & 3) ^ ((lane >> 3) & 3)) << 3;
  const int q = lane & 15;
  const int cg = lane >> 4;
  const int rdoff = ((cg ^ ((q >> 1) & 3)) << 3);
  // stage full A: wave w covers row-groups {2w, 2w+1} x all 4 k-subtiles
  #pragma unroll
  for (int s = 0; s < 8; ++s) {
    int kt = s & 3, rg = 2 * wave + (s >> 2);
    int r = rg * 16 + sr;
    GLOAD16(X + (size_t)(row0 + r) * K + kt * 32 + sc, &lA[kt][rg * 512]);
  }
  const u16* gB0 = WT + (size_t)(wave * 16 + sr) * K + sc;
  const u16* gB1 = WT + (size_t)(64 + wave * 16 + sr) * K + sc;
  u16* lB0 = &lB[wave * 512];
  u16* lB1 = &lB[2048 + wave * 512];
  for (int nc = 0; nc < NCH; ++nc) {
    const size_t nbase = (size_t)nc * 128 * K;
    f32x4 acc[4][4] = {};
    for (int k0 = 0; k0 < K; k0 += 32) {
      __syncthreads();
      GLOAD16(gB0 + nbase + k0, lB0);
      GLOAD16(gB1 + nbase + k0, lB1);
      __syncthreads();          // drains A (first iter) + B
      const int kt = k0 >> 5;
      bf16x8 af[4], bf[4];
      #pragma unroll
      for (int i = 0; i < 4; ++i)
        af[i] = *(const bf16x8*)&lA[kt][(wr + i * 16 + q) * 32 + rdoff];
      #pragma unroll
      for (int j = 0; j < 4; ++j)
        bf[j] = *(const bf16x8*)&lB[(wc + j * 16 + q) * 32 + rdoff];
      #pragma unroll
      for (int i = 0; i < 4; ++i)
        #pragma unroll
        for (int j = 0; j < 4; ++j)
          acc[i][j] = __builtin_amdgcn_mfma_f32_16x16x32_bf16(af[i], bf[j], acc[i][j], 0, 0, 0);
    }
    const int rg4 = cg * 4;
    const float scl = (QS && nc == 0) ? QSCALE : 1.f;
    #pragma unroll
    for (int i = 0; i < 4; ++i) {
      #pragma unroll
      for (int j = 0; j < 4; ++j) {
        int col = nc * 128 + wc + j * 16 + q;
        float bv = bias[col];
        #pragma unroll
        for (int jj = 0; jj < 4; ++jj) {
          int row = row0 + wr + i * 16 + rg4 + jj;
          float v = acc[i][j][jj] + bv;
          if (ACT == 1) v = 0.5f * v * (1.f + erff(v * 0.70710678118654752f));
          if (QS) v *= scl;
          outp[(size_t)row * N + col] = f2bf(v);
        }
      }
    }
  }
}

// ---------------------------------------------------------------- residual GEMM + fused LN (N=128)
__global__ __launch_bounds__(256)
void k_gemm_ln(const u16* __restrict__ X, const u16* __restrict__ WT,
               const float* __restrict__ bias, float* __restrict__ xio,
               const float* __restrict__ g, const float* __restrict__ be,
               u16* __restrict__ srcout, int K) {
  __shared__ __align__(16) u16 lA[128 * 32];
  __shared__ __align__(16) u16 lB[128 * 32];
  __shared__ float part[128][2][2];
  const int tid = threadIdx.x;
  const int wave = tid >> 6, lane = tid & 63;
  const int row0 = blockIdx.x * 128;
  const int wr = (wave >> 1) * 64, wc = (wave & 1) * 64;
  const int whalf = wave & 1;
  const int sr = lane >> 2;
  const int sc = ((lane & 3) ^ ((lane >> 3) & 3)) << 3;
  const u16* gA0 = X  + (size_t)(row0 + wave * 16 + sr) * K + sc;
  const u16* gA1 = X  + (size_t)(row0 + 64 + wave * 16 + sr) * K + sc;
  const u16* gB0 = WT + (size_t)(wave * 16 + sr) * K + sc;
  const u16* gB1 = WT + (size_t)(64 + wave * 16 + sr) * K + sc;
  u16* lA0 = &lA[wave * 512];
  u16* lA1 = &lA[2048 + wave * 512];
  u16* lB0 = &lB[wave * 512];
  u16* lB1 = &lB[2048 + wave * 512];
  const int q = lane & 15;
  const int cg = lane >> 4;
  const int rdoff = ((cg ^ ((q >> 1) & 3)) << 3);
  f32x4 acc[4][4] = {};
  for (int k0 = 0; k0 < K; k0 += 32) {
    __syncthreads();
    GLOAD16(gA0 + k0, lA0);
    GLOAD16(gA1 + k0, lA1);
    GLOAD16(gB0 + k0, lB0);
    GLOAD16(gB1 + k0, lB1);
    __syncthreads();
    bf16x8 af[4], bf[4];
    #pragma unroll
    for (int i = 0; i < 4; ++i)
      af[i] = *(const bf16x8*)&lA[(wr + i * 16 + q) * 32 + rdoff];
    #pragma unroll
    for (int j = 0; j < 4; ++j)
      bf[j] = *(const bf16x8*)&lB[(wc + j * 16 + q) * 32 + rdoff];
    #pragma unroll
    for (int i = 0; i < 4; ++i)
      #pragma unroll
      for (int j = 0; j < 4; ++j)
        acc[i][j] = __builtin_amdgcn_mfma_f32_16x16x32_bf16(af[i], bf[j], acc[i][j], 0, 0, 0);
  }
  const int rg4 = cg * 4;
  float ps[4][4], ps2[4][4];
  #pragma unroll
  for (int i = 0; i < 4; ++i)
    #pragma unroll
    for (int jj = 0; jj < 4; ++jj) { ps[i][jj] = 0.f; ps2[i][jj] = 0.f; }
  #pragma unroll
  for (int i = 0; i < 4; ++i) {
    #pragma unroll
    for (int j = 0; j < 4; ++j) {
      int col = wc + j * 16 + q;
      float bv = bias[col];
      #pragma unroll
      for (int jj = 0; jj < 4; ++jj) {
        int row = row0 + wr + i * 16 + rg4 + jj;
        float xv = xio[(size_t)row * 128 + col] + acc[i][j][jj] + bv;
        acc[i][j][jj] = xv;
        ps[i][jj] += xv;
        ps2[i][jj] += xv * xv;
      }
    }
  }
  #pragma unroll
  for (int o = 1; o < 16; o <<= 1) {
    #pragma unroll
    for (int i = 0; i < 4; ++i)
      #pragma unroll
      for (int jj = 0; jj < 4; ++jj) {
        ps[i][jj]  += __shfl_xor(ps[i][jj], o);
        ps2[i][jj] += __shfl_xor(ps2[i][jj], o);
      }
  }
  if (q == 0) {
    #pragma unroll
    for (int i = 0; i < 4; ++i)
      #pragma unroll
      for (int jj = 0; jj < 4; ++jj) {
        int rl = wr + i * 16 + rg4 + jj;
        part[rl][whalf][0] = ps[i][jj];
        part[rl][whalf][1] = ps2[i][jj];
      }
  }
  __syncthreads();
  #pragma unroll
  for (int i = 0; i < 4; ++i) {
    #pragma unroll
    for (int jj = 0; jj < 4; ++jj) {
      int rl = wr + i * 16 + rg4 + jj;
      float S  = part[rl][0][0] + part[rl][1][0];
      float S2 = part[rl][0][1] + part[rl][1][1];
      float mean = S * (1.f / 128.f);
      float rstd = rsqrtf(S2 * (1.f / 128.f) - mean * mean + 1e-5f);
      int row = row0 + rl;
      #pragma unroll
      for (int j = 0; j < 4; ++j) {
        int col = wc + j * 16 + q;
        float xv = acc[i][j][jj];
        xio[(size_t)row * 128 + col] = xv;
        srcout[(size_t)row * 128 + col] = f2bf((xv - mean) * rstd * g[col] + be[col]);
      }
    }
  }
}

// ---------------------------------------------------------------- attention (32x32 MFMA flash)
// grid (NHEAD, BATCH), 576 threads = 9 waves, one q-tile per wave.
#define VSTR2 296   // Vt row stride (u16)
__global__ __launch_bounds__(576)
void k_attn(const u16* __restrict__ qkv, const int* __restrict__ mask,
            u16* __restrict__ out) {
  int h = blockIdx.x, b = blockIdx.y;
  __shared__ __align__(16) u16 Klin[9 * 512];
  __shared__ __align__(16) u16 Vt[16 * VSTR2];
  __shared__ int part[4];
  const int tid = threadIdx.x;
  if (tid < 256) {
    int mv = (mask[b * SEQL + tid] != 0) ? 1 : 0;
    #pragma unroll
    for (int o = 32; o; o >>= 1) mv += __shfl_xor(mv, o);
    if ((tid & 63) == 0) part[tid >> 6] = mv;
  }
  {
    int r = tid >> 1, h2 = tid & 1;
    uint4 val = make_uint4(0, 0, 0, 0);
    if (r < NPOS)
      val = *(const uint4*)&qkv[((size_t)(b * NPOS + r)) * 384 + h * 16 + 128 + h2 * 8];
    *(uint4*)&Klin[(r >> 5) * 512 + h2 * 256 + (r & 31) * 8] = val;
  }
  if (tid < 288) {
    int r = tid;
    u16 tmp[16];
    if (r < NPOS) {
      const u16* vp = &qkv[((size_t)(b * NPOS + r)) * 384 + h * 16 + 256];
      *(uint4*)&tmp[0] = *(const uint4*)&vp[0];
      *(uint4*)&tmp[8] = *(const uint4*)&vp[8];
    } else {
      #pragma unroll
      for (int d = 0; d < 16; ++d) tmp[d] = 0;
    }
    #pragma unroll
    for (int d = 0; d < 16; ++d) Vt[d * VSTR2 + r] = tmp[d];
  }
  __syncthreads();
  const int nvalid = part[0] + part[1] + part[2] + part[3] + 3;
  const int ktiles = (nvalid + 31) >> 5;
  const int wave = tid >> 6, lane = tid & 63;
  const int q5 = lane & 31, hi = lane >> 5;
  const f32x16 zf = {};
  const int qt = wave;
  int qrow = qt * 32 + q5;
  int qr = (qrow < NPOS) ? qrow : (NPOS - 1);
  bf16x8 qf = *(const bf16x8*)&qkv[((size_t)(b * NPOS + qr)) * 384 + h * 16 + hi * 8];
  float m = -1e30f, l = 0.f;
  f32x16 acc = {};
  for (int kt = 0; kt < ktiles; ++kt) {
    bf16x8 kf = *(const bf16x8*)&Klin[kt * 512 + lane * 8];
    __builtin_amdgcn_s_setprio(1);
    f32x16 s4 = __builtin_amdgcn_mfma_f32_32x32x16_bf16(kf, qf, zf, 0, 0, 0);
    __builtin_amdgcn_s_setprio(0);
    float p[16];
    float tmax = -1e30f;
    #pragma unroll
    for (int r = 0; r < 16; ++r) {
      int kr = kt * 32 + (r & 3) + 8 * (r >> 2) + 4 * hi;
      float v = (kr < nvalid) ? s4[r] : -1e30f;
      p[r] = v;
      tmax = fmaxf(tmax, v);
    }
    tmax = fmaxf(tmax, __shfl_xor(tmax, 32));
    float mnew = fmaxf(m, tmax);
    float fac = exp2f(m - mnew);
    float tsum = 0.f;
    #pragma unroll
    for (int r = 0; r < 16; ++r) { p[r] = exp2f(p[r] - mnew); tsum += p[r]; }
    tsum += __shfl_xor(tsum, 32);
    l = l * fac + tsum;
    m = mnew;
    #pragma unroll
    for (int r = 0; r < 8; ++r) acc[r] *= fac;
    u32 w[8], xw[8];
    #pragma unroll
    for (int i = 0; i < 8; ++i)
      asm("v_cvt_pk_bf16_f32 %0, %1, %2" : "=v"(w[i]) : "v"(p[2 * i]), "v"(p[2 * i + 1]));
    #pragma unroll
    for (int i = 0; i < 8; ++i) xw[i] = (u32)__shfl_xor((int)w[i], 32);
    union { u32 u[4]; bf16x8 v; } f1, f2;
    if (hi) {
      f1.u[0] = xw[2]; f1.u[1] = xw[3]; f1.u[2] = w[2]; f1.u[3] = w[3];
      f2.u[0] = xw[6]; f2.u[1] = xw[7]; f2.u[2] = w[6]; f2.u[3] = w[7];
    } else {
      f1.u[0] = w[0]; f1.u[1] = w[1]; f1.u[2] = xw[0]; f1.u[3] = xw[1];
      f2.u[0] = w[4]; f2.u[1] = w[5]; f2.u[2] = xw[4]; f2.u[3] = xw[5];
    }
    bf16x8 vf0 = {}, vf1 = {};
    if (q5 < 16) {
      vf0 = *(const bf16x8*)&Vt[q5 * VSTR2 + kt * 32 + hi * 8];
      vf1 = *(const bf16x8*)&Vt[q5 * VSTR2 + kt * 32 + 16 + hi * 8];
    }
    __builtin_amdgcn_s_setprio(1);
    acc = __builtin_amdgcn_mfma_f32_32x32x16_bf16(vf0, f1.v, acc, 0, 0, 0);
    acc = __builtin_amdgcn_mfma_f32_32x32x16_bf16(vf1, f2.v, acc, 0, 0, 0);
    __builtin_amdgcn_s_setprio(0);
  }
  if (qrow < NPOS) {
    float linv = 1.f / l;
    u16* op = &out[((size_t)(b * NPOS + qrow)) * HD + h * 16];
    u32 w0 = (u32)f2bf(acc[0] * linv) | ((u32)f2bf(acc[1] * linv) << 16);
    u32 w1 = (u32)f2bf(acc[2] * linv) | ((u32)f2bf(acc[3] * linv) << 16);
    u32 w2 = (u32)f2bf(acc[4] * linv) | ((u32)f2bf(acc[5] * linv) << 16);
    u32 w3 = (u32)f2bf(acc[6] * linv) | ((u32)f2bf(acc[7] * linv) << 16);
    *(uint2*)&op[4 * hi] = make_uint2(w0, w1);
    *(uint2*)&op[8 + 4 * hi] = make_uint2(w2, w3);
  }
}

// ---------------------------------------------------------------- head
__global__ __launch_bounds__(128)
void k_head(const float* __restrict__ x, const float* __restrict__ bw,
            const float* __restrict__ bb, const float* __restrict__ cw,
            const float* __restrict__ cb, float* __restrict__ dout) {
  int b = blockIdx.x, n = threadIdx.x;
  __shared__ float lat[HD];
  __shared__ float redp[2], redss[2];
  float lv = x[((size_t)b * NPOS) * HD + n];
  lat[n] = lv;
  __syncthreads();
  float t = 0.f;
  for (int k = 0; k < HD; ++k) t += lat[k] * bw[k * HD + n];
  t += bb[n];
  t = fmaxf(t, 0.f);
  float p = t * cw[n];
  float ss = lv * lv;
  #pragma unroll
  for (int o = 32; o; o >>= 1) { p += __shfl_xor(p, o); ss += __shfl_xor(ss, o); }
  if ((n & 63) == 0) { redp[n >> 6] = p; redss[n >> 6] = ss; }
  __syncthreads();
  float psum = redp[0] + redp[1];
  float ssum = redss[0] + redss[1];
  if (n == 0) dout[b] = psum + cb[0];
  float nrm = fmaxf(sqrtf(ssum), 1e-12f);
  dout[256 + (size_t)b * HD + n] = lv / nrm;
}

// ---------------------------------------------------------------- launch
extern "C" void kernel_launch(void* const* d_in, const int* in_sizes, int n_in,
                              void* d_out, int out_size, void* d_ws, size_t ws_size,
                              hipStream_t stream) {
  const int* item_seq = (const int*)d_in[0];
  const int* action_seq = (const int*)d_in[1];
  const int* time_diff = (const int*)d_in[2];
  const int* mask = (const int*)d_in[3];
  const int* u_cv = (const int*)d_in[4];
  const int* u_cl = (const int*)d_in[5];
  const float* u_num = (const float*)d_in[6];
  const int* i_cv = (const int*)d_in[7];
  const int* i_cl = (const int*)d_in[8];
  const float* i_num = (const float*)d_in[9];
  const float* item_t = (const float*)d_in[10];
  const float* act_t = (const float*)d_in[11];
  const float* time_t = (const float*)d_in[12];
  const float* cat_t = (const float*)d_in[13];
  const float* num_W = (const float*)d_in[14];
  const float* gtok = (const float*)d_in[15];
  const float* ln1_g = (const float*)d_in[16];
  const float* ln1_b = (const float*)d_in[17];
  const float* qkv_w = (const float*)d_in[18];
  const float* qkv_b = (const float*)d_in[19];
  const float* out_w = (const float*)d_in[20];
  const float* out_b = (const float*)d_in[21];
  const float* w1 = (const float*)d_in[22];
  const float* b1 = (const float*)d_in[23];
  const float* w2 = (const float*)d_in[24];
  const float* b2 = (const float*)d_in[25];
  const float* ln2_g = (const float*)d_in[26];
  const float* ln2_b = (const float*)d_in[27];
  const float* bott_w = (const float*)d_in[28];
  const float* bott_b = (const float*)d_in[29];
  const float* cls_w = (const float*)d_in[30];
  const float* cls_b = (const float*)d_in[31];

  // workspace layout (bytes)
  const size_t off_x   = 0;                    // TTOK*128 f32  = 33,947,648
  const size_t off_src = 33947648;             // TTOK*128 bf16 = 16,973,824
  const size_t off_big = 50921472;             // TTOK*512 bf16 = 67,895,296
  const size_t off_wT  = 118816768;            // 786,432 elems bf16
  const size_t need    = 120389632;
  if (ws_size < need) {
    fprintf(stderr, "kernel_launch: ws_size %zu < needed %zu\n", ws_size, need);
    return;
  }
  char* ws = (char*)d_ws;
  float* x   = (float*)(ws + off_x);
  u16* src   = (u16*)(ws + off_src);
  u16* big   = (u16*)(ws + off_big);
  u16* wT    = (u16*)(ws + off_wT);
  u16* qkvT  = wT;                 // [4][384][128]
  u16* outT  = wT + 196608;        // [4][128][128]
  u16* w1T   = wT + 262144;        // [4][512][128]
  u16* w2T   = wT + 524288;        // [4][128][512]

  k_transpose_all<<<3072, 256, 0, stream>>>(qkv_w, out_w, w1, w2, wT);

  k_build<<<dim3(NPOS, BATCH), 128, 0, stream>>>(
      item_seq, action_seq, time_diff, u_cv, u_cl, u_num, i_cv, i_cl, i_num,
      item_t, act_t, time_t, cat_t, num_W, gtok, ln1_g, ln1_b, x, src);

  const int rt = TTOK / 128;  // 518
  for (int dd = 0; dd < DEPTH; ++dd) {
    // QKV (q cols pre-scaled by QSCALE): src -> big  (A-resident, 3 n-chunks)
    k_gemm_nres<3, 0, true><<<rt, 256, 0, stream>>>(
        src, qkvT + dd * 49152, qkv_b + dd * 384, big);
    // attention: big -> src
    k_attn<<<dim3(NHEAD, BATCH), 576, 0, stream>>>(big, mask, src);
    // proj + residual + fused LN2: src(attn) -> x, src(LN2 out)
    k_gemm_ln<<<dim3(rt, 1), 256, 0, stream>>>(
        src, outT + dd * 16384, out_b + dd * HD, x,
        ln2_g + dd * HD, ln2_b + dd * HD, src, 128);
    // MLP1 (gelu): src -> big  (A-resident, 4 n-chunks)
    k_gemm_nres<4, 1, false><<<rt, 256, 0, stream>>>(
        src, w1T + dd * 65536, b1 + dd * FF, big);
    // MLP2 + residual + fused LN1 of next layer: big -> x, src
    const float* ng = (dd < 3) ? (ln1_g + (dd + 1) * HD) : (ln1_g + dd * HD);
    const float* nb = (dd < 3) ? (ln1_b + (dd + 1) * HD) : (ln1_b + dd * HD);
    k_gemm_ln<<<dim3(rt, 1), 256, 0, stream>>>(
        big, w2T + dd * 65536, b2 + dd * HD, x, ng, nb, src, 512);
  }

  k_head<<<BATCH, 128, 0, stream>>>(x, bott_w, bott_b, cls_w, cls_b, (float*)d_out);
}